// Round 7
// baseline (953.543 us; speedup 1.0000x reference)
//
#include <hip/hip_runtime.h>
#include <stdint.h>

#define B_SZ  32
#define T_SZ  2048
#define IN_D  128
#define HID   512
#define NCHAIN 410              // ceil(T/5)
#define INV_TAUX 0.005f         // 1/200

typedef __attribute__((ext_vector_type(8))) short bf16x8;
typedef __attribute__((ext_vector_type(4))) float f32x4;
typedef __attribute__((ext_vector_type(4))) float float4v;
typedef __attribute__((ext_vector_type(8))) unsigned short u16x8;

#define MFMA(a, b, c) __builtin_amdgcn_mfma_f32_16x16x32_bf16((a), (b), (c), 0, 0, 0)

__device__ __forceinline__ unsigned short f2bf(float x) {
  union { float f; unsigned int u; } v; v.f = x;
  unsigned int r = v.u + 0x7FFFu + ((v.u >> 16) & 1u);  // RNE
  return (unsigned short)(r >> 16);
}
__device__ __forceinline__ float bf2f(unsigned short b) {
  union { unsigned int u; float f; } v; v.u = ((unsigned int)b) << 16;
  return v.f;
}
__device__ __forceinline__ float fast_tanh(float x) {
  float ax = fabsf(x);
  float e = __expf(-2.0f * ax);
  float r = (1.0f - e) / (1.0f + e);
  return x < 0.0f ? -r : r;
}
__device__ __forceinline__ void gload_lds16(const void* g, void* l) {
  __builtin_amdgcn_global_load_lds(
      reinterpret_cast<__attribute__((address_space(1))) void*>(reinterpret_cast<uintptr_t>(g)),
      reinterpret_cast<__attribute__((address_space(3))) void*>(reinterpret_cast<uintptr_t>(l)),
      16, 0, 0);
}

// ---------------------------------------------------------------------------
// Weights are stored FRAGMENT-LINEAR: for matrix (N x K), element
//   flat[((nf*nk + kk)*64 + lane)*8 + e] = B[nf*16 + (lane&15)][kk*32 + (lane>>4)*8 + e]
// so one wave's B-fragment load = contiguous 1KB (perfectly coalesced).
// nk = K/32. Offsets in wt[]: We1t@0(nk=4), We2t@65536, We3t@327680,
// Wd1t@589824, Wd2t@851968(N=128), Wrec@917504 (all nk=16).
// ---------------------------------------------------------------------------

// ---------------------------------------------------------------------------
// Fused 3-layer encoder. 512 thr = 8 waves (2m x 4n), 64 rows/block.
// ---------------------------------------------------------------------------
__global__ __launch_bounds__(512, 2) void enc_fused_k(
    const float* __restrict__ in_seq,
    const unsigned short* __restrict__ wt,
    const float* __restrict__ be1, const float* __restrict__ be2,
    const float* __restrict__ be3,
    unsigned short* __restrict__ xseq)
{
  __shared__ __attribute__((aligned(16))) unsigned short sA[64 * 128];  // 16 KB
  __shared__ __attribute__((aligned(16))) unsigned short sH[64 * 512];  // 64 KB

  const int tid = threadIdx.x;
  const int m0 = blockIdx.x * 64;
  const int wave = tid >> 6, lane = tid & 63;
  const int wm = wave >> 2, wn = wave & 3;
  const int lrow = lane & 15, lhi = lane >> 4, sw = lrow & 7;

  // stage input tile f32 -> bf16, chunk-swizzled
#pragma unroll
  for (int p = 0; p < 2; ++p) {
    int id = (p << 9) + tid;
    int row = id >> 4, cc = id & 15;
    const float* src = in_seq + (size_t)(m0 + row) * IN_D + (cc << 3);
    float4v u0 = *(const float4v*)src;
    float4v u1 = *(const float4v*)(src + 4);
    u16x8 h;
    h[0] = f2bf(u0[0]); h[1] = f2bf(u0[1]); h[2] = f2bf(u0[2]); h[3] = f2bf(u0[3]);
    h[4] = f2bf(u1[0]); h[5] = f2bf(u1[1]); h[6] = f2bf(u1[2]); h[7] = f2bf(u1[3]);
    int slot = (cc & 8) | ((cc & 7) ^ (row & 7));
    *(u16x8*)(sA + (row << 7) + (slot << 3)) = h;
  }
  __syncthreads();

  f32x4 acc[2][8];
  const unsigned short* Bts[3] = {wt, wt + 65536, wt + 327680};
  const float* bss[3] = {be1, be2, be3};

  for (int l = 0; l < 3; ++l) {
    const unsigned short* lsrc = (l == 0) ? sA : sH;
    const int lstr = (l == 0) ? 128 : 512;
    const int nk = (l == 0) ? 4 : 16;
    const unsigned short* bl = Bts[l] + (lane << 3);
    const int nfb = ((wn << 3)) * nk;
    const float* bias = bss[l];

#pragma unroll
    for (int m = 0; m < 2; ++m)
#pragma unroll
      for (int n = 0; n < 8; ++n) acc[m][n] = (f32x4){0.f, 0.f, 0.f, 0.f};

    bf16x8 b0[8], b1[8];
#pragma unroll
    for (int n = 0; n < 8; ++n)
      b0[n] = *(const bf16x8*)(bl + ((nfb + n * nk) << 9));

    for (int kk = 0; kk < nk; kk += 2) {
#pragma unroll
      for (int n = 0; n < 8; ++n)
        b1[n] = *(const bf16x8*)(bl + ((nfb + n * nk + kk + 1) << 9));
      {
        const int c = (kk << 2) + lhi;
        const int slot = (c & ~7) | ((c & 7) ^ sw);
        bf16x8 af0 = *(const bf16x8*)(lsrc + (wm * 32 + lrow) * lstr + (slot << 3));
        bf16x8 af1 = *(const bf16x8*)(lsrc + (wm * 32 + 16 + lrow) * lstr + (slot << 3));
#pragma unroll
        for (int n = 0; n < 8; ++n) {
          acc[0][n] = MFMA(af0, b0[n], acc[0][n]);
          acc[1][n] = MFMA(af1, b0[n], acc[1][n]);
        }
      }
      if (kk + 2 < nk) {
#pragma unroll
        for (int n = 0; n < 8; ++n)
          b0[n] = *(const bf16x8*)(bl + ((nfb + n * nk + kk + 2) << 9));
      }
      {
        const int c = ((kk + 1) << 2) + lhi;
        const int slot = (c & ~7) | ((c & 7) ^ sw);
        bf16x8 af0 = *(const bf16x8*)(lsrc + (wm * 32 + lrow) * lstr + (slot << 3));
        bf16x8 af1 = *(const bf16x8*)(lsrc + (wm * 32 + 16 + lrow) * lstr + (slot << 3));
#pragma unroll
        for (int n = 0; n < 8; ++n) {
          acc[0][n] = MFMA(af0, b1[n], acc[0][n]);
          acc[1][n] = MFMA(af1, b1[n], acc[1][n]);
        }
      }
    }
    __syncthreads();
#pragma unroll
    for (int n = 0; n < 8; ++n) {
      const int col = (wn << 7) + n * 16 + lrow;
      const float bv = bias[col];
      const int c2 = col >> 3, e = col & 7;
#pragma unroll
      for (int m = 0; m < 2; ++m)
#pragma unroll
        for (int q = 0; q < 4; ++q) {
          const int row = wm * 32 + m * 16 + (lhi << 2) + q;
          const int slot2 = (c2 & ~7) | ((c2 & 7) ^ (row & 7));
          sH[(row << 9) + (slot2 << 3) + e] = f2bf(fast_tanh(acc[m][n][q] + bv));
        }
    }
    __syncthreads();
  }

  // coalesced un-swizzling copy sH -> xseq
#pragma unroll
  for (int p = 0; p < 8; ++p) {
    int id = (p << 9) + tid;
    int row = id >> 6, cc = id & 63;
    int slot = (cc & ~7) | ((cc & 7) ^ (row & 7));
    u16x8 v = *(const u16x8*)(sH + (row << 9) + (slot << 3));
    *(u16x8*)(xseq + ((size_t)(m0 + row) << 9) + (cc << 3)) = v;
  }
}

// ---------------------------------------------------------------------------
// Fused 2-layer decoder. 512 thr = 8 waves (2m x 4n), 64 rows/block.
// ---------------------------------------------------------------------------
__global__ __launch_bounds__(512, 2) void dec_fused_k(
    const unsigned short* __restrict__ X,
    const unsigned short* __restrict__ Wd1t,
    const unsigned short* __restrict__ Wd2t,
    const float* __restrict__ bd1, const float* __restrict__ bd2,
    float* __restrict__ out)
{
  __shared__ __attribute__((aligned(16))) unsigned short sX[64 * 512];  // 64 KB
  __shared__ __attribute__((aligned(16))) unsigned short sH[64 * 512];  // 64 KB

  const int tid = threadIdx.x;
  const int m0 = blockIdx.x * 64;
  const int wave = tid >> 6, lane = tid & 63;
  const int wm = wave >> 2, wn = wave & 3;
  const int lrow = lane & 15, lhi = lane >> 4, sw = lrow & 7;

  char* lX = (char*)sX + tid * 16;
#pragma unroll
  for (int p = 0; p < 8; ++p) {
    int id = (p << 9) + tid;
    int row = id >> 6, cc = id & 63;
    int gcc = (cc & ~7) | ((cc & 7) ^ (row & 7));
    gload_lds16(X + ((size_t)(m0 + row) << 9) + (gcc << 3), lX + (p << 13));
  }
  __syncthreads();

  // ---- layer 1: K=512, N=512 ----
  f32x4 acc[2][8];
#pragma unroll
  for (int m = 0; m < 2; ++m)
#pragma unroll
    for (int n = 0; n < 8; ++n) acc[m][n] = (f32x4){0.f, 0.f, 0.f, 0.f};

  {
    const unsigned short* bl = Wd1t + (lane << 3);
    const int nfb = (wn << 3) << 4;
    bf16x8 b0[8], b1[8];
#pragma unroll
    for (int n = 0; n < 8; ++n)
      b0[n] = *(const bf16x8*)(bl + ((nfb + (n << 4)) << 9));
    for (int kk = 0; kk < 16; kk += 2) {
#pragma unroll
      for (int n = 0; n < 8; ++n)
        b1[n] = *(const bf16x8*)(bl + ((nfb + (n << 4) + kk + 1) << 9));
      {
        const int c = (kk << 2) + lhi;
        const int slot = (c & ~7) | ((c & 7) ^ sw);
        bf16x8 af0 = *(const bf16x8*)(sX + ((wm * 32 + lrow) << 9) + (slot << 3));
        bf16x8 af1 = *(const bf16x8*)(sX + ((wm * 32 + 16 + lrow) << 9) + (slot << 3));
#pragma unroll
        for (int n = 0; n < 8; ++n) {
          acc[0][n] = MFMA(af0, b0[n], acc[0][n]);
          acc[1][n] = MFMA(af1, b0[n], acc[1][n]);
        }
      }
      if (kk + 2 < 16) {
#pragma unroll
        for (int n = 0; n < 8; ++n)
          b0[n] = *(const bf16x8*)(bl + ((nfb + (n << 4) + kk + 2) << 9));
      }
      {
        const int c = ((kk + 1) << 2) + lhi;
        const int slot = (c & ~7) | ((c & 7) ^ sw);
        bf16x8 af0 = *(const bf16x8*)(sX + ((wm * 32 + lrow) << 9) + (slot << 3));
        bf16x8 af1 = *(const bf16x8*)(sX + ((wm * 32 + 16 + lrow) << 9) + (slot << 3));
#pragma unroll
        for (int n = 0; n < 8; ++n) {
          acc[0][n] = MFMA(af0, b1[n], acc[0][n]);
          acc[1][n] = MFMA(af1, b1[n], acc[1][n]);
        }
      }
    }
  }
  __syncthreads();
#pragma unroll
  for (int n = 0; n < 8; ++n) {
    const int col = (wn << 7) + n * 16 + lrow;
    const float bv = bd1[col];
    const int c2 = col >> 3, e = col & 7;
#pragma unroll
    for (int m = 0; m < 2; ++m)
#pragma unroll
      for (int q = 0; q < 4; ++q) {
        const int row = wm * 32 + m * 16 + (lhi << 2) + q;
        const int slot2 = (c2 & ~7) | ((c2 & 7) ^ (row & 7));
        sH[(row << 9) + (slot2 << 3) + e] = f2bf(fast_tanh(acc[m][n][q] + bv));
      }
  }
  __syncthreads();

  // ---- layer 2: K=512, N=128 ----
  f32x4 acc2[2][2];
#pragma unroll
  for (int m = 0; m < 2; ++m)
#pragma unroll
    for (int n = 0; n < 2; ++n) acc2[m][n] = (f32x4){0.f, 0.f, 0.f, 0.f};

  {
    const unsigned short* bl = Wd2t + (lane << 3);
    const int nfb = (wn << 1) << 4;
    bf16x8 c0[2], c1[2];
#pragma unroll
    for (int n = 0; n < 2; ++n)
      c0[n] = *(const bf16x8*)(bl + ((nfb + (n << 4)) << 9));
    for (int kk = 0; kk < 16; kk += 2) {
#pragma unroll
      for (int n = 0; n < 2; ++n)
        c1[n] = *(const bf16x8*)(bl + ((nfb + (n << 4) + kk + 1) << 9));
      {
        const int c = (kk << 2) + lhi;
        const int slot = (c & ~7) | ((c & 7) ^ sw);
        bf16x8 af0 = *(const bf16x8*)(sH + ((wm * 32 + lrow) << 9) + (slot << 3));
        bf16x8 af1 = *(const bf16x8*)(sH + ((wm * 32 + 16 + lrow) << 9) + (slot << 3));
#pragma unroll
        for (int n = 0; n < 2; ++n) {
          acc2[0][n] = MFMA(af0, c0[n], acc2[0][n]);
          acc2[1][n] = MFMA(af1, c0[n], acc2[1][n]);
        }
      }
      if (kk + 2 < 16) {
#pragma unroll
        for (int n = 0; n < 2; ++n)
          c0[n] = *(const bf16x8*)(bl + ((nfb + (n << 4) + kk + 2) << 9));
      }
      {
        const int c = ((kk + 1) << 2) + lhi;
        const int slot = (c & ~7) | ((c & 7) ^ sw);
        bf16x8 af0 = *(const bf16x8*)(sH + ((wm * 32 + lrow) << 9) + (slot << 3));
        bf16x8 af1 = *(const bf16x8*)(sH + ((wm * 32 + 16 + lrow) << 9) + (slot << 3));
#pragma unroll
        for (int n = 0; n < 2; ++n) {
          acc2[0][n] = MFMA(af0, c1[n], acc2[0][n]);
          acc2[1][n] = MFMA(af1, c1[n], acc2[1][n]);
        }
      }
    }
  }
#pragma unroll
  for (int n = 0; n < 2; ++n) {
    const int col = (wn << 5) + n * 16 + lrow;
    const float bv = bd2[col];
#pragma unroll
    for (int m = 0; m < 2; ++m)
#pragma unroll
      for (int q = 0; q < 4; ++q) {
        const int row = wm * 32 + m * 16 + (lhi << 2) + q;
        out[(size_t)(m0 + row) * IN_D + col] = fast_tanh(acc2[m][n][q] + bv);
      }
  }
}

// ---------------------------------------------------------------------------
// Persistent recurrence: block = one chain (32 rows). State in REGISTERS
// (32 f32/thread, C/D-fragment layout). LDS = 32KB tanh/staging tile only.
// ALL global traffic is u16x8-coalesced (fixes write-allocate RMW disaster).
// ---------------------------------------------------------------------------
__global__ __launch_bounds__(512, 1) void rec_k(
    const unsigned short* __restrict__ Wrec,
    unsigned short* __restrict__ xsall)
{
  __shared__ __attribute__((aligned(16))) unsigned short sT[32 * 512];  // 32 KB

  const int tid = threadIdx.x;
  const int chain = blockIdx.x;
  const int t0 = chain * 5;
  const int wave = tid >> 6, lane = tid & 63;
  const int wm = wave >> 2, wn = wave & 3;
  const int lrow = lane & 15, lhi = lane >> 4, sw = lrow & 7;

  // coalesced init: xsall[row, t0, :] -> sT (linear)
#pragma unroll
  for (int p = 0; p < 4; ++p) {
    int id = (p << 9) + tid;
    int row = id >> 6, c8 = id & 63;
    u16x8 v = *(const u16x8*)(xsall + (((size_t)row * T_SZ + t0) << 9) + (c8 << 3));
    *(u16x8*)(sT + (row << 9) + (c8 << 3)) = v;
  }
  __syncthreads();

  // pick into state regs: st[n][q] = x[row=wm*16+(lhi<<2)+q][col=(wn<<7)+n*16+lrow]
  float st[8][4];
#pragma unroll
  for (int n = 0; n < 8; ++n) {
    const int col = (wn << 7) + n * 16 + lrow;
#pragma unroll
    for (int q = 0; q < 4; ++q) {
      const int row = wm * 16 + (lhi << 2) + q;
      st[n][q] = bf2f(sT[(row << 9) + col]);
    }
  }
  __syncthreads();

  const unsigned short* bl = Wrec + (lane << 3);
  const int nfb = (wn << 3) << 4;

  for (int s = 0; s < 5; ++s) {
    // stage tanh(st) -> sT (swizzled chunks, LDS-only scatter)
#pragma unroll
    for (int n = 0; n < 8; ++n) {
      const int col = (wn << 7) + n * 16 + lrow;
      const int c2 = col >> 3, e = col & 7;
#pragma unroll
      for (int q = 0; q < 4; ++q) {
        const int row = wm * 16 + (lhi << 2) + q;
        const int slot2 = (c2 & ~7) | ((c2 & 7) ^ (row & 7));
        sT[(row << 9) + (slot2 << 3) + e] = f2bf(fast_tanh(st[n][q]));
      }
    }
    __syncthreads();

    f32x4 acc[8];
#pragma unroll
    for (int n = 0; n < 8; ++n) acc[n] = (f32x4){0.f, 0.f, 0.f, 0.f};

    bf16x8 b0[8], b1[8];
#pragma unroll
    for (int n = 0; n < 8; ++n)
      b0[n] = *(const bf16x8*)(bl + ((nfb + (n << 4)) << 9));
    for (int kk = 0; kk < 16; kk += 2) {
#pragma unroll
      for (int n = 0; n < 8; ++n)
        b1[n] = *(const bf16x8*)(bl + ((nfb + (n << 4) + kk + 1) << 9));
      {
        const int c = (kk << 2) + lhi;
        const int slot = (c & ~7) | ((c & 7) ^ sw);
        bf16x8 af = *(const bf16x8*)(sT + ((wm * 16 + lrow) << 9) + (slot << 3));
#pragma unroll
        for (int n = 0; n < 8; ++n) acc[n] = MFMA(af, b0[n], acc[n]);
      }
      if (kk + 2 < 16) {
#pragma unroll
        for (int n = 0; n < 8; ++n)
          b0[n] = *(const bf16x8*)(bl + ((nfb + (n << 4) + kk + 2) << 9));
      }
      {
        const int c = ((kk + 1) << 2) + lhi;
        const int slot = (c & ~7) | ((c & 7) ^ sw);
        bf16x8 af = *(const bf16x8*)(sT + ((wm * 16 + lrow) << 9) + (slot << 3));
#pragma unroll
        for (int n = 0; n < 8; ++n) acc[n] = MFMA(af, b1[n], acc[n]);
      }
    }
    __syncthreads();   // all waves done reading sT

    // update state regs + write xnew bf16 into sT (linear layout)
#pragma unroll
    for (int n = 0; n < 8; ++n) {
      const int col = (wn << 7) + n * 16 + lrow;
#pragma unroll
      for (int q = 0; q < 4; ++q) {
        const int row = wm * 16 + (lhi << 2) + q;
        const float x = st[n][q];
        const float xn = x + (acc[n][q] - x) * INV_TAUX;
        st[n][q] = xn;
        sT[(row << 9) + col] = f2bf(xn);
      }
    }
    __syncthreads();

    // coalesced dump sT -> xsall[:, t, :]
    const int t = t0 + s;
    if (t < T_SZ) {
#pragma unroll
      for (int p = 0; p < 4; ++p) {
        int id = (p << 9) + tid;
        int row = id >> 6, c8 = id & 63;
        u16x8 v = *(const u16x8*)(sT + (row << 9) + (c8 << 3));
        *(u16x8*)(xsall + (((size_t)row * T_SZ + t) << 9) + (c8 << 3)) = v;
      }
    }
    __syncthreads();   // protect sT before next step's staging
  }
}

// weight prep into fragment-linear layout
__global__ void prep_k(const float* __restrict__ We1, const float* __restrict__ We2,
                       const float* __restrict__ We3, const float* __restrict__ Wd1,
                       const float* __restrict__ Wd2, const float* __restrict__ W,
                       unsigned short* __restrict__ wt) {
  int idx = blockIdx.x * blockDim.x + threadIdx.x;
  if (idx >= 1179648) return;
  unsigned short v;
  if (idx < 65536) {
    int i = idx, lane = (i >> 3) & 63, t2 = i >> 9;
    int kk = t2 & 3, nf = t2 >> 2;
    int n = (nf << 4) + (lane & 15), k = (kk << 5) + ((lane >> 4) << 3) + (i & 7);
    v = f2bf(We1[k * 512 + n]);
  } else if (idx < 327680) {
    int i = idx - 65536, lane = (i >> 3) & 63, t2 = i >> 9;
    int kk = t2 & 15, nf = t2 >> 4;
    int n = (nf << 4) + (lane & 15), k = (kk << 5) + ((lane >> 4) << 3) + (i & 7);
    v = f2bf(We2[k * 512 + n]);
  } else if (idx < 589824) {
    int i = idx - 327680, lane = (i >> 3) & 63, t2 = i >> 9;
    int kk = t2 & 15, nf = t2 >> 4;
    int n = (nf << 4) + (lane & 15), k = (kk << 5) + ((lane >> 4) << 3) + (i & 7);
    v = f2bf(We3[k * 512 + n]);
  } else if (idx < 851968) {
    int i = idx - 589824, lane = (i >> 3) & 63, t2 = i >> 9;
    int kk = t2 & 15, nf = t2 >> 4;
    int n = (nf << 4) + (lane & 15), k = (kk << 5) + ((lane >> 4) << 3) + (i & 7);
    v = f2bf(Wd1[k * 512 + n]);
  } else if (idx < 917504) {
    int i = idx - 851968, lane = (i >> 3) & 63, t2 = i >> 9;
    int kk = t2 & 15, nf = t2 >> 4;
    int n = (nf << 4) + (lane & 15), k = (kk << 5) + ((lane >> 4) << 3) + (i & 7);
    v = f2bf(Wd2[k * 128 + n]);
  } else {
    int i = idx - 917504, lane = (i >> 3) & 63, t2 = i >> 9;
    int kk = t2 & 15, nf = t2 >> 4;
    int n = (nf << 4) + (lane & 15), k = (kk << 5) + ((lane >> 4) << 3) + (i & 7);
    v = f2bf(W[(n << 9) + k]);
  }
  wt[idx] = v;
}

__global__ void sentinel_k(float* out, float v) { out[0] = v; }

extern "C" void kernel_launch(void* const* d_in, const int* in_sizes, int n_in,
                              void* d_out, int out_size, void* d_ws, size_t ws_size,
                              hipStream_t stream) {
  const float* in_seq = (const float*)d_in[0];
  const float* We1 = (const float*)d_in[1];
  const float* be1 = (const float*)d_in[2];
  const float* We2 = (const float*)d_in[3];
  const float* be2 = (const float*)d_in[4];
  const float* We3 = (const float*)d_in[5];
  const float* be3 = (const float*)d_in[6];
  const float* Wd1 = (const float*)d_in[7];
  const float* bd1 = (const float*)d_in[8];
  const float* Wd2 = (const float*)d_in[9];
  const float* bd2 = (const float*)d_in[10];
  const float* W   = (const float*)d_in[11];

  const int NROW = B_SZ * T_SZ;                       // 65536
  const size_t OFF_XSEQ = 0;                          // 67,108,864 B
  const size_t OFF_WT   = (size_t)NROW * HID * 2;     // 67,108,864
  const size_t REQUIRED = OFF_WT + 2359296;           // 69,468,160

  float* outp = (float*)d_out;
  float* outr = outp + (size_t)NROW * IN_D;

  if (ws_size < REQUIRED) {
    sentinel_k<<<1, 1, 0, stream>>>(outp, (float)(ws_size >> 20));
    return;
  }

  char* ws = (char*)d_ws;
  unsigned short* xseq = (unsigned short*)(ws + OFF_XSEQ);  // reused as xsall
  unsigned short* wt   = (unsigned short*)(ws + OFF_WT);
  unsigned short* Wd1t = wt + 589824;
  unsigned short* Wd2t = wt + 851968;
  unsigned short* Wrec = wt + 917504;

  prep_k<<<4608, 256, 0, stream>>>(We1, We2, We3, Wd1, Wd2, W, wt);
  enc_fused_k<<<1024, 512, 0, stream>>>(in_seq, wt, be1, be2, be3, xseq);
  dec_fused_k<<<1024, 512, 0, stream>>>(xseq, Wd1t, Wd2t, bd1, bd2, outr);
  rec_k<<<NCHAIN, 512, 0, stream>>>(Wrec, xseq);
  dec_fused_k<<<1024, 512, 0, stream>>>(xseq, Wd1t, Wd2t, bd1, bd2, outp);
}

// Round 8
// 572.877 us; speedup vs baseline: 1.6645x; 1.6645x over previous
//
#include <hip/hip_runtime.h>
#include <stdint.h>

#define B_SZ  32
#define T_SZ  2048
#define IN_D  128
#define HID   512
#define NCHAIN 410              // ceil(T/5)
#define MREC  (NCHAIN * B_SZ)   // 13120
#define INV_TAUX 0.005f         // 1/200

typedef __attribute__((ext_vector_type(8))) short bf16x8;
typedef __attribute__((ext_vector_type(4))) float f32x4;
typedef __attribute__((ext_vector_type(4))) float float4v;
typedef __attribute__((ext_vector_type(8))) unsigned short u16x8;

#define MFMA(a, b, c) __builtin_amdgcn_mfma_f32_16x16x32_bf16((a), (b), (c), 0, 0, 0)

__device__ __forceinline__ unsigned short f2bf(float x) {
  union { float f; unsigned int u; } v; v.f = x;
  unsigned int r = v.u + 0x7FFFu + ((v.u >> 16) & 1u);  // RNE
  return (unsigned short)(r >> 16);
}
__device__ __forceinline__ float bf2f(unsigned short b) {
  union { unsigned int u; float f; } v; v.u = ((unsigned int)b) << 16;
  return v.f;
}
__device__ __forceinline__ float fast_tanh(float x) {
  float ax = fabsf(x);
  float e = __expf(-2.0f * ax);
  float r = (1.0f - e) / (1.0f + e);
  return x < 0.0f ? -r : r;
}
__device__ __forceinline__ void gload_lds16(const void* g, void* l) {
  __builtin_amdgcn_global_load_lds(
      reinterpret_cast<__attribute__((address_space(1))) void*>(reinterpret_cast<uintptr_t>(g)),
      reinterpret_cast<__attribute__((address_space(3))) void*>(reinterpret_cast<uintptr_t>(l)),
      16, 0, 0);
}

// ---------------------------------------------------------------------------
// Weights are stored FRAGMENT-LINEAR: for matrix (N x K), element
//   flat[((nf*nk + kk)*64 + lane)*8 + e] = B[nf*16 + (lane&15)][kk*32 + (lane>>4)*8 + e]
// nk = K/32. Offsets in wt[]: We1t@0(nk=4), We2t@65536, We3t@327680,
// Wd1t@589824, Wd2t@851968(N=128), Wrec@917504 (all nk=16).
// ---------------------------------------------------------------------------

// ---------------------------------------------------------------------------
// Fused 3-layer encoder. 512 thr = 8 waves (2m x 4n), 64 rows/block.
// ---------------------------------------------------------------------------
__global__ __launch_bounds__(512, 2) void enc_fused_k(
    const float* __restrict__ in_seq,
    const unsigned short* __restrict__ wt,
    const float* __restrict__ be1, const float* __restrict__ be2,
    const float* __restrict__ be3,
    unsigned short* __restrict__ xseq)
{
  __shared__ __attribute__((aligned(16))) unsigned short sA[64 * 128];  // 16 KB
  __shared__ __attribute__((aligned(16))) unsigned short sH[64 * 512];  // 64 KB

  const int tid = threadIdx.x;
  const int m0 = blockIdx.x * 64;
  const int wave = tid >> 6, lane = tid & 63;
  const int wm = wave >> 2, wn = wave & 3;
  const int lrow = lane & 15, lhi = lane >> 4, sw = lrow & 7;

#pragma unroll
  for (int p = 0; p < 2; ++p) {
    int id = (p << 9) + tid;
    int row = id >> 4, cc = id & 15;
    const float* src = in_seq + (size_t)(m0 + row) * IN_D + (cc << 3);
    float4v u0 = *(const float4v*)src;
    float4v u1 = *(const float4v*)(src + 4);
    u16x8 h;
    h[0] = f2bf(u0[0]); h[1] = f2bf(u0[1]); h[2] = f2bf(u0[2]); h[3] = f2bf(u0[3]);
    h[4] = f2bf(u1[0]); h[5] = f2bf(u1[1]); h[6] = f2bf(u1[2]); h[7] = f2bf(u1[3]);
    int slot = (cc & 8) | ((cc & 7) ^ (row & 7));
    *(u16x8*)(sA + (row << 7) + (slot << 3)) = h;
  }
  __syncthreads();

  f32x4 acc[2][8];
  const unsigned short* Bts[3] = {wt, wt + 65536, wt + 327680};
  const float* bss[3] = {be1, be2, be3};

  for (int l = 0; l < 3; ++l) {
    const unsigned short* lsrc = (l == 0) ? sA : sH;
    const int lstr = (l == 0) ? 128 : 512;
    const int nk = (l == 0) ? 4 : 16;
    const unsigned short* bl = Bts[l] + (lane << 3);
    const int nfb = ((wn << 3)) * nk;
    const float* bias = bss[l];

#pragma unroll
    for (int m = 0; m < 2; ++m)
#pragma unroll
      for (int n = 0; n < 8; ++n) acc[m][n] = (f32x4){0.f, 0.f, 0.f, 0.f};

    bf16x8 b0[8], b1[8];
#pragma unroll
    for (int n = 0; n < 8; ++n)
      b0[n] = *(const bf16x8*)(bl + ((nfb + n * nk) << 9));

    for (int kk = 0; kk < nk; kk += 2) {
#pragma unroll
      for (int n = 0; n < 8; ++n)
        b1[n] = *(const bf16x8*)(bl + ((nfb + n * nk + kk + 1) << 9));
      {
        const int c = (kk << 2) + lhi;
        const int slot = (c & ~7) | ((c & 7) ^ sw);
        bf16x8 af0 = *(const bf16x8*)(lsrc + (wm * 32 + lrow) * lstr + (slot << 3));
        bf16x8 af1 = *(const bf16x8*)(lsrc + (wm * 32 + 16 + lrow) * lstr + (slot << 3));
#pragma unroll
        for (int n = 0; n < 8; ++n) {
          acc[0][n] = MFMA(af0, b0[n], acc[0][n]);
          acc[1][n] = MFMA(af1, b0[n], acc[1][n]);
        }
      }
      if (kk + 2 < nk) {
#pragma unroll
        for (int n = 0; n < 8; ++n)
          b0[n] = *(const bf16x8*)(bl + ((nfb + n * nk + kk + 2) << 9));
      }
      {
        const int c = ((kk + 1) << 2) + lhi;
        const int slot = (c & ~7) | ((c & 7) ^ sw);
        bf16x8 af0 = *(const bf16x8*)(lsrc + (wm * 32 + lrow) * lstr + (slot << 3));
        bf16x8 af1 = *(const bf16x8*)(lsrc + (wm * 32 + 16 + lrow) * lstr + (slot << 3));
#pragma unroll
        for (int n = 0; n < 8; ++n) {
          acc[0][n] = MFMA(af0, b1[n], acc[0][n]);
          acc[1][n] = MFMA(af1, b1[n], acc[1][n]);
        }
      }
    }
    __syncthreads();
#pragma unroll
    for (int n = 0; n < 8; ++n) {
      const int col = (wn << 7) + n * 16 + lrow;
      const float bv = bias[col];
      const int c2 = col >> 3, e = col & 7;
#pragma unroll
      for (int m = 0; m < 2; ++m)
#pragma unroll
        for (int q = 0; q < 4; ++q) {
          const int row = wm * 32 + m * 16 + (lhi << 2) + q;
          const int slot2 = (c2 & ~7) | ((c2 & 7) ^ (row & 7));
          sH[(row << 9) + (slot2 << 3) + e] = f2bf(fast_tanh(acc[m][n][q] + bv));
        }
    }
    __syncthreads();
  }

#pragma unroll
  for (int p = 0; p < 8; ++p) {
    int id = (p << 9) + tid;
    int row = id >> 6, cc = id & 63;
    int slot = (cc & ~7) | ((cc & 7) ^ (row & 7));
    u16x8 v = *(const u16x8*)(sH + (row << 9) + (slot << 3));
    *(u16x8*)(xseq + ((size_t)(m0 + row) << 9) + (cc << 3)) = v;
  }
}

// ---------------------------------------------------------------------------
// Fused 2-layer decoder. 512 thr = 8 waves (2m x 4n), 64 rows/block.
// ---------------------------------------------------------------------------
__global__ __launch_bounds__(512, 2) void dec_fused_k(
    const unsigned short* __restrict__ X,
    const unsigned short* __restrict__ Wd1t,
    const unsigned short* __restrict__ Wd2t,
    const float* __restrict__ bd1, const float* __restrict__ bd2,
    float* __restrict__ out)
{
  __shared__ __attribute__((aligned(16))) unsigned short sX[64 * 512];  // 64 KB
  __shared__ __attribute__((aligned(16))) unsigned short sH[64 * 512];  // 64 KB

  const int tid = threadIdx.x;
  const int m0 = blockIdx.x * 64;
  const int wave = tid >> 6, lane = tid & 63;
  const int wm = wave >> 2, wn = wave & 3;
  const int lrow = lane & 15, lhi = lane >> 4, sw = lrow & 7;

  char* lX = (char*)sX + tid * 16;
#pragma unroll
  for (int p = 0; p < 8; ++p) {
    int id = (p << 9) + tid;
    int row = id >> 6, cc = id & 63;
    int gcc = (cc & ~7) | ((cc & 7) ^ (row & 7));
    gload_lds16(X + ((size_t)(m0 + row) << 9) + (gcc << 3), lX + (p << 13));
  }
  __syncthreads();

  f32x4 acc[2][8];
#pragma unroll
  for (int m = 0; m < 2; ++m)
#pragma unroll
    for (int n = 0; n < 8; ++n) acc[m][n] = (f32x4){0.f, 0.f, 0.f, 0.f};

  {
    const unsigned short* bl = Wd1t + (lane << 3);
    const int nfb = (wn << 3) << 4;
    bf16x8 b0[8], b1[8];
#pragma unroll
    for (int n = 0; n < 8; ++n)
      b0[n] = *(const bf16x8*)(bl + ((nfb + (n << 4)) << 9));
    for (int kk = 0; kk < 16; kk += 2) {
#pragma unroll
      for (int n = 0; n < 8; ++n)
        b1[n] = *(const bf16x8*)(bl + ((nfb + (n << 4) + kk + 1) << 9));
      {
        const int c = (kk << 2) + lhi;
        const int slot = (c & ~7) | ((c & 7) ^ sw);
        bf16x8 af0 = *(const bf16x8*)(sX + ((wm * 32 + lrow) << 9) + (slot << 3));
        bf16x8 af1 = *(const bf16x8*)(sX + ((wm * 32 + 16 + lrow) << 9) + (slot << 3));
#pragma unroll
        for (int n = 0; n < 8; ++n) {
          acc[0][n] = MFMA(af0, b0[n], acc[0][n]);
          acc[1][n] = MFMA(af1, b0[n], acc[1][n]);
        }
      }
      if (kk + 2 < 16) {
#pragma unroll
        for (int n = 0; n < 8; ++n)
          b0[n] = *(const bf16x8*)(bl + ((nfb + (n << 4) + kk + 2) << 9));
      }
      {
        const int c = ((kk + 1) << 2) + lhi;
        const int slot = (c & ~7) | ((c & 7) ^ sw);
        bf16x8 af0 = *(const bf16x8*)(sX + ((wm * 32 + lrow) << 9) + (slot << 3));
        bf16x8 af1 = *(const bf16x8*)(sX + ((wm * 32 + 16 + lrow) << 9) + (slot << 3));
#pragma unroll
        for (int n = 0; n < 8; ++n) {
          acc[0][n] = MFMA(af0, b1[n], acc[0][n]);
          acc[1][n] = MFMA(af1, b1[n], acc[1][n]);
        }
      }
    }
  }
  __syncthreads();
#pragma unroll
  for (int n = 0; n < 8; ++n) {
    const int col = (wn << 7) + n * 16 + lrow;
    const float bv = bd1[col];
    const int c2 = col >> 3, e = col & 7;
#pragma unroll
    for (int m = 0; m < 2; ++m)
#pragma unroll
      for (int q = 0; q < 4; ++q) {
        const int row = wm * 32 + m * 16 + (lhi << 2) + q;
        const int slot2 = (c2 & ~7) | ((c2 & 7) ^ (row & 7));
        sH[(row << 9) + (slot2 << 3) + e] = f2bf(fast_tanh(acc[m][n][q] + bv));
      }
  }
  __syncthreads();

  f32x4 acc2[2][2];
#pragma unroll
  for (int m = 0; m < 2; ++m)
#pragma unroll
    for (int n = 0; n < 2; ++n) acc2[m][n] = (f32x4){0.f, 0.f, 0.f, 0.f};

  {
    const unsigned short* bl = Wd2t + (lane << 3);
    const int nfb = (wn << 1) << 4;
    bf16x8 c0[2], c1[2];
#pragma unroll
    for (int n = 0; n < 2; ++n)
      c0[n] = *(const bf16x8*)(bl + ((nfb + (n << 4)) << 9));
    for (int kk = 0; kk < 16; kk += 2) {
#pragma unroll
      for (int n = 0; n < 2; ++n)
        c1[n] = *(const bf16x8*)(bl + ((nfb + (n << 4) + kk + 1) << 9));
      {
        const int c = (kk << 2) + lhi;
        const int slot = (c & ~7) | ((c & 7) ^ sw);
        bf16x8 af0 = *(const bf16x8*)(sH + ((wm * 32 + lrow) << 9) + (slot << 3));
        bf16x8 af1 = *(const bf16x8*)(sH + ((wm * 32 + 16 + lrow) << 9) + (slot << 3));
#pragma unroll
        for (int n = 0; n < 2; ++n) {
          acc2[0][n] = MFMA(af0, c0[n], acc2[0][n]);
          acc2[1][n] = MFMA(af1, c0[n], acc2[1][n]);
        }
      }
      if (kk + 2 < 16) {
#pragma unroll
        for (int n = 0; n < 2; ++n)
          c0[n] = *(const bf16x8*)(bl + ((nfb + (n << 4) + kk + 2) << 9));
      }
      {
        const int c = ((kk + 1) << 2) + lhi;
        const int slot = (c & ~7) | ((c & 7) ^ sw);
        bf16x8 af0 = *(const bf16x8*)(sH + ((wm * 32 + lrow) << 9) + (slot << 3));
        bf16x8 af1 = *(const bf16x8*)(sH + ((wm * 32 + 16 + lrow) << 9) + (slot << 3));
#pragma unroll
        for (int n = 0; n < 2; ++n) {
          acc2[0][n] = MFMA(af0, c1[n], acc2[0][n]);
          acc2[1][n] = MFMA(af1, c1[n], acc2[1][n]);
        }
      }
    }
  }
#pragma unroll
  for (int n = 0; n < 2; ++n) {
    const int col = (wn << 5) + n * 16 + lrow;
    const float bv = bd2[col];
#pragma unroll
    for (int m = 0; m < 2; ++m)
#pragma unroll
      for (int q = 0; q < 4; ++q) {
        const int row = wm * 32 + m * 16 + (lhi << 2) + q;
        out[(size_t)(m0 + row) * IN_D + col] = fast_tanh(acc2[m][n][q] + bv);
      }
  }
}

// ---------------------------------------------------------------------------
// Recurrence step (one launch per step s): block = one chain (32 rows x 512).
// A = tanh(st_in) staged once into LDS (fused f32->tanh->bf16, swizzled);
// 8 waves each own 64 cols (no B duplication, no y-replication).
// Epilogue: xnew = x + (mfma - x)/TAU_X; writes st_out f32 + xsall bf16.
// ~100 VGPR -- no spills (the round-6/7 persistent kernels spilled).
// ---------------------------------------------------------------------------
__global__ __launch_bounds__(512, 2) void rec2_k(
    const unsigned short* __restrict__ Wrec,  // fragment-linear, nk=16
    const float* __restrict__ st_in,
    float* __restrict__ st_out,
    unsigned short* __restrict__ xsall,
    int s)
{
  __shared__ __attribute__((aligned(16))) unsigned short sA[32 * 512];  // 32 KB

  const int tid = threadIdx.x;
  const int chain = blockIdx.x;
  const int wave = tid >> 6, lane = tid & 63;
  const int wn = wave;                                  // 8 waves over N=512
  const int lrow = lane & 15, lhi = lane >> 4, sw = lrow & 7;
  const size_t rbase = (size_t)chain * 32;

  // stage tanh(st_in) -> sA: LDS slot (row, cc) holds global chunk cc^(row&7)
#pragma unroll
  for (int p = 0; p < 4; ++p) {
    int id = (p << 9) + tid;
    int row = id >> 6, cc = id & 63;
    int gc = (cc & ~7) | ((cc & 7) ^ (row & 7));
    const float* src = st_in + (rbase + row) * HID + (gc << 3);
    float4v u0 = *(const float4v*)src;
    float4v u1 = *(const float4v*)(src + 4);
    u16x8 h;
    h[0] = f2bf(fast_tanh(u0[0])); h[1] = f2bf(fast_tanh(u0[1]));
    h[2] = f2bf(fast_tanh(u0[2])); h[3] = f2bf(fast_tanh(u0[3]));
    h[4] = f2bf(fast_tanh(u1[0])); h[5] = f2bf(fast_tanh(u1[1]));
    h[6] = f2bf(fast_tanh(u1[2])); h[7] = f2bf(fast_tanh(u1[3]));
    *(u16x8*)(sA + (row << 9) + (cc << 3)) = h;
  }
  __syncthreads();

  f32x4 acc[2][4];
#pragma unroll
  for (int m = 0; m < 2; ++m)
#pragma unroll
    for (int n = 0; n < 4; ++n) acc[m][n] = (f32x4){0.f, 0.f, 0.f, 0.f};

  const unsigned short* bl = Wrec + (lane << 3);
  const int nfb = (wn << 2) << 4;                       // wn*4 nf, nk=16

  bf16x8 b0[4], b1[4];
#pragma unroll
  for (int n = 0; n < 4; ++n)
    b0[n] = *(const bf16x8*)(bl + ((nfb + (n << 4)) << 9));
  for (int kk = 0; kk < 16; kk += 2) {
#pragma unroll
    for (int n = 0; n < 4; ++n)
      b1[n] = *(const bf16x8*)(bl + ((nfb + (n << 4) + kk + 1) << 9));
    {
      const int c = (kk << 2) + lhi;
      const int slot = (c & ~7) | ((c & 7) ^ sw);
      bf16x8 af0 = *(const bf16x8*)(sA + (lrow << 9) + (slot << 3));
      bf16x8 af1 = *(const bf16x8*)(sA + ((16 + lrow) << 9) + (slot << 3));
#pragma unroll
      for (int n = 0; n < 4; ++n) {
        acc[0][n] = MFMA(af0, b0[n], acc[0][n]);
        acc[1][n] = MFMA(af1, b0[n], acc[1][n]);
      }
    }
    if (kk + 2 < 16) {
#pragma unroll
      for (int n = 0; n < 4; ++n)
        b0[n] = *(const bf16x8*)(bl + ((nfb + (n << 4) + kk + 2) << 9));
    }
    {
      const int c = ((kk + 1) << 2) + lhi;
      const int slot = (c & ~7) | ((c & 7) ^ sw);
      bf16x8 af0 = *(const bf16x8*)(sA + (lrow << 9) + (slot << 3));
      bf16x8 af1 = *(const bf16x8*)(sA + ((16 + lrow) << 9) + (slot << 3));
#pragma unroll
      for (int n = 0; n < 4; ++n) {
        acc[0][n] = MFMA(af0, b1[n], acc[0][n]);
        acc[1][n] = MFMA(af1, b1[n], acc[1][n]);
      }
    }
  }

  // epilogue: update state + emit pred-state at t = chain*5 + s
  const int t = chain * 5 + s;
#pragma unroll
  for (int n = 0; n < 4; ++n) {
    const int col = (wn << 6) + n * 16 + lrow;
#pragma unroll
    for (int m = 0; m < 2; ++m)
#pragma unroll
      for (int q = 0; q < 4; ++q) {
        const int row = m * 16 + (lhi << 2) + q;
        const size_t gi = (rbase + row) * HID + col;
        const float x = st_in[gi];
        const float xn = x + (acc[m][n][q] - x) * INV_TAUX;
        st_out[gi] = xn;
        if (t < T_SZ)
          xsall[((size_t)row * T_SZ + t) * HID + col] = f2bf(xn);
      }
  }
}

// chain starts: st0[chain*32+b, c] = bf2f(xseq[b, 5*chain, c])
__global__ void chain_init_k(const unsigned short* __restrict__ xseq,
                             float* __restrict__ st0) {
  int idx = blockIdx.x * blockDim.x + threadIdx.x;
  if (idx >= MREC * HID) return;
  int r = idx >> 9;
  int c = idx & 511;
  int chain = r >> 5;
  int b = r & 31;
  st0[idx] = bf2f(xseq[((size_t)b * T_SZ + chain * 5) * HID + c]);
}

// weight prep into fragment-linear layout
__global__ void prep_k(const float* __restrict__ We1, const float* __restrict__ We2,
                       const float* __restrict__ We3, const float* __restrict__ Wd1,
                       const float* __restrict__ Wd2, const float* __restrict__ W,
                       unsigned short* __restrict__ wt) {
  int idx = blockIdx.x * blockDim.x + threadIdx.x;
  if (idx >= 1179648) return;
  unsigned short v;
  if (idx < 65536) {
    int i = idx, lane = (i >> 3) & 63, t2 = i >> 9;
    int kk = t2 & 3, nf = t2 >> 2;
    int n = (nf << 4) + (lane & 15), k = (kk << 5) + ((lane >> 4) << 3) + (i & 7);
    v = f2bf(We1[k * 512 + n]);
  } else if (idx < 327680) {
    int i = idx - 65536, lane = (i >> 3) & 63, t2 = i >> 9;
    int kk = t2 & 15, nf = t2 >> 4;
    int n = (nf << 4) + (lane & 15), k = (kk << 5) + ((lane >> 4) << 3) + (i & 7);
    v = f2bf(We2[k * 512 + n]);
  } else if (idx < 589824) {
    int i = idx - 327680, lane = (i >> 3) & 63, t2 = i >> 9;
    int kk = t2 & 15, nf = t2 >> 4;
    int n = (nf << 4) + (lane & 15), k = (kk << 5) + ((lane >> 4) << 3) + (i & 7);
    v = f2bf(We3[k * 512 + n]);
  } else if (idx < 851968) {
    int i = idx - 589824, lane = (i >> 3) & 63, t2 = i >> 9;
    int kk = t2 & 15, nf = t2 >> 4;
    int n = (nf << 4) + (lane & 15), k = (kk << 5) + ((lane >> 4) << 3) + (i & 7);
    v = f2bf(Wd1[k * 512 + n]);
  } else if (idx < 917504) {
    int i = idx - 851968, lane = (i >> 3) & 63, t2 = i >> 9;
    int kk = t2 & 15, nf = t2 >> 4;
    int n = (nf << 4) + (lane & 15), k = (kk << 5) + ((lane >> 4) << 3) + (i & 7);
    v = f2bf(Wd2[k * 128 + n]);
  } else {
    int i = idx - 917504, lane = (i >> 3) & 63, t2 = i >> 9;
    int kk = t2 & 15, nf = t2 >> 4;
    int n = (nf << 4) + (lane & 15), k = (kk << 5) + ((lane >> 4) << 3) + (i & 7);
    v = f2bf(W[(n << 9) + k]);
  }
  wt[idx] = v;
}

__global__ void sentinel_k(float* out, float v) { out[0] = v; }

extern "C" void kernel_launch(void* const* d_in, const int* in_sizes, int n_in,
                              void* d_out, int out_size, void* d_ws, size_t ws_size,
                              hipStream_t stream) {
  const float* in_seq = (const float*)d_in[0];
  const float* We1 = (const float*)d_in[1];
  const float* be1 = (const float*)d_in[2];
  const float* We2 = (const float*)d_in[3];
  const float* be2 = (const float*)d_in[4];
  const float* We3 = (const float*)d_in[5];
  const float* be3 = (const float*)d_in[6];
  const float* Wd1 = (const float*)d_in[7];
  const float* bd1 = (const float*)d_in[8];
  const float* Wd2 = (const float*)d_in[9];
  const float* bd2 = (const float*)d_in[10];
  const float* W   = (const float*)d_in[11];

  const int NROW = B_SZ * T_SZ;                       // 65536
  const size_t OFF_XSEQ = 0;                          // 67,108,864 B
  const size_t OFF_WT   = (size_t)NROW * HID * 2;     // 67,108,864
  const size_t OFF_ST0  = OFF_WT + 2359296;           // 69,468,160
  const size_t OFF_ST1  = OFF_ST0 + (size_t)MREC * HID * 4;  // 96,337,920
  const size_t REQUIRED = OFF_ST1 + (size_t)MREC * HID * 4;  // 123,207,680

  float* outp = (float*)d_out;
  float* outr = outp + (size_t)NROW * IN_D;

  if (ws_size < REQUIRED) {
    sentinel_k<<<1, 1, 0, stream>>>(outp, (float)(ws_size >> 20));
    return;
  }

  char* ws = (char*)d_ws;
  unsigned short* xseq = (unsigned short*)(ws + OFF_XSEQ);  // reused as xsall
  unsigned short* wt   = (unsigned short*)(ws + OFF_WT);
  unsigned short* Wd1t = wt + 589824;
  unsigned short* Wd2t = wt + 851968;
  unsigned short* Wrec = wt + 917504;
  float* st0 = (float*)(ws + OFF_ST0);
  float* st1 = (float*)(ws + OFF_ST1);

  prep_k<<<4608, 256, 0, stream>>>(We1, We2, We3, Wd1, Wd2, W, wt);
  enc_fused_k<<<1024, 512, 0, stream>>>(in_seq, wt, be1, be2, be3, xseq);
  dec_fused_k<<<1024, 512, 0, stream>>>(xseq, Wd1t, Wd2t, bd1, bd2, outr);
  chain_init_k<<<(MREC * HID + 255) / 256, 256, 0, stream>>>(xseq, st0);
  for (int s = 0; s < 5; ++s) {
    const float* sIn  = (s & 1) ? st1 : st0;
    float*       sOut = (s & 1) ? st0 : st1;
    rec2_k<<<NCHAIN, 512, 0, stream>>>(Wrec, sIn, sOut, xseq, s);
  }
  dec_fused_k<<<1024, 512, 0, stream>>>(xseq, Wd1t, Wd2t, bd1, bd2, outp);
}

// Round 9
// 447.080 us; speedup vs baseline: 2.1328x; 1.2814x over previous
//
#include <hip/hip_runtime.h>
#include <stdint.h>

#define B_SZ  32
#define T_SZ  2048
#define IN_D  128
#define HID   512
#define NCHAIN 410              // ceil(T/5)
#define MREC  (NCHAIN * B_SZ)   // 13120
#define INV_TAUX 0.005f         // 1/200

typedef __attribute__((ext_vector_type(8))) short bf16x8;
typedef __attribute__((ext_vector_type(4))) float f32x4;
typedef __attribute__((ext_vector_type(4))) float float4v;
typedef __attribute__((ext_vector_type(8))) unsigned short u16x8;

#define MFMA(a, b, c) __builtin_amdgcn_mfma_f32_16x16x32_bf16((a), (b), (c), 0, 0, 0)

__device__ __forceinline__ unsigned short f2bf(float x) {
  union { float f; unsigned int u; } v; v.f = x;
  unsigned int r = v.u + 0x7FFFu + ((v.u >> 16) & 1u);  // RNE
  return (unsigned short)(r >> 16);
}
__device__ __forceinline__ float bf2f(unsigned short b) {
  union { unsigned int u; float f; } v; v.u = ((unsigned int)b) << 16;
  return v.f;
}
__device__ __forceinline__ float fast_tanh(float x) {
  float ax = fabsf(x);
  float e = __expf(-2.0f * ax);
  float r = (1.0f - e) * __builtin_amdgcn_rcpf(1.0f + e);  // rcp: ~1e-7 rel err
  return x < 0.0f ? -r : r;
}
__device__ __forceinline__ void gload_lds16(const void* g, void* l) {
  __builtin_amdgcn_global_load_lds(
      reinterpret_cast<__attribute__((address_space(1))) void*>(reinterpret_cast<uintptr_t>(g)),
      reinterpret_cast<__attribute__((address_space(3))) void*>(reinterpret_cast<uintptr_t>(l)),
      16, 0, 0);
}

// ---------------------------------------------------------------------------
// Weights FRAGMENT-LINEAR: for (N x K), flat[((nf*nk + kk)*64 + lane)*8 + e]
//   = B[nf*16 + (lane&15)][kk*32 + (lane>>4)*8 + e],  nk = K/32.
// wt[] offsets: We1t@0(nk=4), We2t@65536, We3t@327680, Wd1t@589824,
// Wd2t@851968(N=128), Wrec@917504 (all nk=16).
// Wave layout is 1m x 8n: each wave owns ALL 64 rows x its own 64-col slice
// (nf = wn*4 .. wn*4+3) -> zero cross-wave B duplication (L2-BW was the cap).
// ---------------------------------------------------------------------------

// ---------------------------------------------------------------------------
// Fused 3-layer encoder. 512 thr = 8 waves, 64 rows/block, acc[4][4]/wave.
// ---------------------------------------------------------------------------
__global__ __launch_bounds__(512, 2) void enc_fused_k(
    const float* __restrict__ in_seq,
    const unsigned short* __restrict__ wt,
    const float* __restrict__ be1, const float* __restrict__ be2,
    const float* __restrict__ be3,
    unsigned short* __restrict__ xseq)
{
  __shared__ __attribute__((aligned(16))) unsigned short sA[64 * 128];  // 16 KB
  __shared__ __attribute__((aligned(16))) unsigned short sH[64 * 512];  // 64 KB

  const int tid = threadIdx.x;
  const int m0 = blockIdx.x * 64;
  const int wave = tid >> 6, lane = tid & 63;
  const int wn = wave;
  const int lrow = lane & 15, lhi = lane >> 4, sw = lrow & 7;

  // stage input tile f32 -> bf16, chunk-swizzled
#pragma unroll
  for (int p = 0; p < 2; ++p) {
    int id = (p << 9) + tid;
    int row = id >> 4, cc = id & 15;
    const float* src = in_seq + (size_t)(m0 + row) * IN_D + (cc << 3);
    float4v u0 = *(const float4v*)src;
    float4v u1 = *(const float4v*)(src + 4);
    u16x8 h;
    h[0] = f2bf(u0[0]); h[1] = f2bf(u0[1]); h[2] = f2bf(u0[2]); h[3] = f2bf(u0[3]);
    h[4] = f2bf(u1[0]); h[5] = f2bf(u1[1]); h[6] = f2bf(u1[2]); h[7] = f2bf(u1[3]);
    int slot = (cc & 8) | ((cc & 7) ^ (row & 7));
    *(u16x8*)(sA + (row << 7) + (slot << 3)) = h;
  }
  __syncthreads();

  f32x4 acc[4][4];
  const unsigned short* Bts[3] = {wt, wt + 65536, wt + 327680};
  const float* bss[3] = {be1, be2, be3};

  for (int l = 0; l < 3; ++l) {
    const unsigned short* lsrc = (l == 0) ? sA : sH;
    const int lstr = (l == 0) ? 128 : 512;
    const int nk = (l == 0) ? 4 : 16;
    const unsigned short* bl = Bts[l] + (lane << 3);
    const int nfb = (wn << 2) * nk;          // first nf * nk
    const float* bias = bss[l];

#pragma unroll
    for (int m = 0; m < 4; ++m)
#pragma unroll
      for (int n = 0; n < 4; ++n) acc[m][n] = (f32x4){0.f, 0.f, 0.f, 0.f};

    bf16x8 b0[4], b1[4];
#pragma unroll
    for (int n = 0; n < 4; ++n)
      b0[n] = *(const bf16x8*)(bl + ((nfb + n * nk) << 9));

    for (int kk = 0; kk < nk; kk += 2) {
#pragma unroll
      for (int n = 0; n < 4; ++n)
        b1[n] = *(const bf16x8*)(bl + ((nfb + n * nk + kk + 1) << 9));
      {
        const int c = (kk << 2) + lhi;
        const int slot = (c & ~7) | ((c & 7) ^ sw);
        bf16x8 af[4];
#pragma unroll
        for (int m = 0; m < 4; ++m)
          af[m] = *(const bf16x8*)(lsrc + (m * 16 + lrow) * lstr + (slot << 3));
#pragma unroll
        for (int n = 0; n < 4; ++n)
#pragma unroll
          for (int m = 0; m < 4; ++m)
            acc[m][n] = MFMA(af[m], b0[n], acc[m][n]);
      }
      if (kk + 2 < nk) {
#pragma unroll
        for (int n = 0; n < 4; ++n)
          b0[n] = *(const bf16x8*)(bl + ((nfb + n * nk + kk + 2) << 9));
      }
      {
        const int c = ((kk + 1) << 2) + lhi;
        const int slot = (c & ~7) | ((c & 7) ^ sw);
        bf16x8 af[4];
#pragma unroll
        for (int m = 0; m < 4; ++m)
          af[m] = *(const bf16x8*)(lsrc + (m * 16 + lrow) * lstr + (slot << 3));
#pragma unroll
        for (int n = 0; n < 4; ++n)
#pragma unroll
          for (int m = 0; m < 4; ++m)
            acc[m][n] = MFMA(af[m], b1[n], acc[m][n]);
      }
    }
    __syncthreads();
    // epilogue: tanh(acc+bias) -> sH (swizzled bf16); wave's 64-col slice
#pragma unroll
    for (int n = 0; n < 4; ++n) {
      const int col = (wn << 6) + n * 16 + lrow;
      const float bv = bias[col];
      const int c2 = col >> 3, e = col & 7;
#pragma unroll
      for (int m = 0; m < 4; ++m)
#pragma unroll
        for (int q = 0; q < 4; ++q) {
          const int row = m * 16 + (lhi << 2) + q;
          const int slot2 = (c2 & ~7) | ((c2 & 7) ^ (row & 7));
          sH[(row << 9) + (slot2 << 3) + e] = f2bf(fast_tanh(acc[m][n][q] + bv));
        }
    }
    __syncthreads();
  }

  // coalesced un-swizzling copy sH -> xseq
#pragma unroll
  for (int p = 0; p < 8; ++p) {
    int id = (p << 9) + tid;
    int row = id >> 6, cc = id & 63;
    int slot = (cc & ~7) | ((cc & 7) ^ (row & 7));
    u16x8 v = *(const u16x8*)(sH + (row << 9) + (slot << 3));
    *(u16x8*)(xseq + ((size_t)(m0 + row) << 9) + (cc << 3)) = v;
  }
}

// ---------------------------------------------------------------------------
// Fused 2-layer decoder. 512 thr = 8 waves, 64 rows/block, 1m x 8n.
// ---------------------------------------------------------------------------
__global__ __launch_bounds__(512, 2) void dec_fused_k(
    const unsigned short* __restrict__ X,
    const unsigned short* __restrict__ Wd1t,
    const unsigned short* __restrict__ Wd2t,
    const float* __restrict__ bd1, const float* __restrict__ bd2,
    float* __restrict__ out)
{
  __shared__ __attribute__((aligned(16))) unsigned short sX[64 * 512];  // 64 KB
  __shared__ __attribute__((aligned(16))) unsigned short sH[64 * 512];  // 64 KB

  const int tid = threadIdx.x;
  const int m0 = blockIdx.x * 64;
  const int wave = tid >> 6, lane = tid & 63;
  const int wn = wave;
  const int lrow = lane & 15, lhi = lane >> 4, sw = lrow & 7;

  char* lX = (char*)sX + tid * 16;
#pragma unroll
  for (int p = 0; p < 8; ++p) {
    int id = (p << 9) + tid;
    int row = id >> 6, cc = id & 63;
    int gcc = (cc & ~7) | ((cc & 7) ^ (row & 7));
    gload_lds16(X + ((size_t)(m0 + row) << 9) + (gcc << 3), lX + (p << 13));
  }
  __syncthreads();

  // ---- layer 1: K=512, N=512, acc[4][4] ----
  f32x4 acc[4][4];
#pragma unroll
  for (int m = 0; m < 4; ++m)
#pragma unroll
    for (int n = 0; n < 4; ++n) acc[m][n] = (f32x4){0.f, 0.f, 0.f, 0.f};

  {
    const unsigned short* bl = Wd1t + (lane << 3);
    const int nfb = (wn << 2) << 4;          // (wn*4)*16
    bf16x8 b0[4], b1[4];
#pragma unroll
    for (int n = 0; n < 4; ++n)
      b0[n] = *(const bf16x8*)(bl + ((nfb + (n << 4)) << 9));
    for (int kk = 0; kk < 16; kk += 2) {
#pragma unroll
      for (int n = 0; n < 4; ++n)
        b1[n] = *(const bf16x8*)(bl + ((nfb + (n << 4) + kk + 1) << 9));
      {
        const int c = (kk << 2) + lhi;
        const int slot = (c & ~7) | ((c & 7) ^ sw);
        bf16x8 af[4];
#pragma unroll
        for (int m = 0; m < 4; ++m)
          af[m] = *(const bf16x8*)(sX + ((m * 16 + lrow) << 9) + (slot << 3));
#pragma unroll
        for (int n = 0; n < 4; ++n)
#pragma unroll
          for (int m = 0; m < 4; ++m)
            acc[m][n] = MFMA(af[m], b0[n], acc[m][n]);
      }
      if (kk + 2 < 16) {
#pragma unroll
        for (int n = 0; n < 4; ++n)
          b0[n] = *(const bf16x8*)(bl + ((nfb + (n << 4) + kk + 2) << 9));
      }
      {
        const int c = ((kk + 1) << 2) + lhi;
        const int slot = (c & ~7) | ((c & 7) ^ sw);
        bf16x8 af[4];
#pragma unroll
        for (int m = 0; m < 4; ++m)
          af[m] = *(const bf16x8*)(sX + ((m * 16 + lrow) << 9) + (slot << 3));
#pragma unroll
        for (int n = 0; n < 4; ++n)
#pragma unroll
          for (int m = 0; m < 4; ++m)
            acc[m][n] = MFMA(af[m], b1[n], acc[m][n]);
      }
    }
  }
  __syncthreads();
#pragma unroll
  for (int n = 0; n < 4; ++n) {
    const int col = (wn << 6) + n * 16 + lrow;
    const float bv = bd1[col];
    const int c2 = col >> 3, e = col & 7;
#pragma unroll
    for (int m = 0; m < 4; ++m)
#pragma unroll
      for (int q = 0; q < 4; ++q) {
        const int row = m * 16 + (lhi << 2) + q;
        const int slot2 = (c2 & ~7) | ((c2 & 7) ^ (row & 7));
        sH[(row << 9) + (slot2 << 3) + e] = f2bf(fast_tanh(acc[m][n][q] + bv));
      }
  }
  __syncthreads();

  // ---- layer 2: K=512, N=128; wave owns one 16-col frag (nf = wn) ----
  f32x4 acc2[4];
#pragma unroll
  for (int m = 0; m < 4; ++m) acc2[m] = (f32x4){0.f, 0.f, 0.f, 0.f};

  {
    const unsigned short* bl = Wd2t + (lane << 3);
    const int nfb = wn << 4;                 // wn*16
    bf16x8 c0, c1;
    c0 = *(const bf16x8*)(bl + ((nfb + 0) << 9));
    for (int kk = 0; kk < 16; kk += 2) {
      c1 = *(const bf16x8*)(bl + ((nfb + kk + 1) << 9));
      {
        const int c = (kk << 2) + lhi;
        const int slot = (c & ~7) | ((c & 7) ^ sw);
#pragma unroll
        for (int m = 0; m < 4; ++m) {
          bf16x8 af = *(const bf16x8*)(sH + ((m * 16 + lrow) << 9) + (slot << 3));
          acc2[m] = MFMA(af, c0, acc2[m]);
        }
      }
      if (kk + 2 < 16)
        c0 = *(const bf16x8*)(bl + ((nfb + kk + 2) << 9));
      {
        const int c = ((kk + 1) << 2) + lhi;
        const int slot = (c & ~7) | ((c & 7) ^ sw);
#pragma unroll
        for (int m = 0; m < 4; ++m) {
          bf16x8 af = *(const bf16x8*)(sH + ((m * 16 + lrow) << 9) + (slot << 3));
          acc2[m] = MFMA(af, c1, acc2[m]);
        }
      }
    }
  }
  // epilogue 2 -> out (f32)
  {
    const int col = (wn << 4) + lrow;
    const float bv = bd2[col];
#pragma unroll
    for (int m = 0; m < 4; ++m)
#pragma unroll
      for (int q = 0; q < 4; ++q) {
        const int row = m * 16 + (lhi << 2) + q;
        out[(size_t)(m0 + row) * IN_D + col] = fast_tanh(acc2[m][q] + bv);
      }
  }
}

// ---------------------------------------------------------------------------
// Recurrence step (one launch per step s): block = one chain (32 rows x 512).
// ---------------------------------------------------------------------------
__global__ __launch_bounds__(512, 2) void rec2_k(
    const unsigned short* __restrict__ Wrec,  // fragment-linear, nk=16
    const float* __restrict__ st_in,
    float* __restrict__ st_out,
    unsigned short* __restrict__ xsall,
    int s)
{
  __shared__ __attribute__((aligned(16))) unsigned short sA[32 * 512];  // 32 KB

  const int tid = threadIdx.x;
  const int chain = blockIdx.x;
  const int wave = tid >> 6, lane = tid & 63;
  const int wn = wave;                                  // 8 waves over N=512
  const int lrow = lane & 15, lhi = lane >> 4, sw = lrow & 7;
  const size_t rbase = (size_t)chain * 32;

#pragma unroll
  for (int p = 0; p < 4; ++p) {
    int id = (p << 9) + tid;
    int row = id >> 6, cc = id & 63;
    int gc = (cc & ~7) | ((cc & 7) ^ (row & 7));
    const float* src = st_in + (rbase + row) * HID + (gc << 3);
    float4v u0 = *(const float4v*)src;
    float4v u1 = *(const float4v*)(src + 4);
    u16x8 h;
    h[0] = f2bf(fast_tanh(u0[0])); h[1] = f2bf(fast_tanh(u0[1]));
    h[2] = f2bf(fast_tanh(u0[2])); h[3] = f2bf(fast_tanh(u0[3]));
    h[4] = f2bf(fast_tanh(u1[0])); h[5] = f2bf(fast_tanh(u1[1]));
    h[6] = f2bf(fast_tanh(u1[2])); h[7] = f2bf(fast_tanh(u1[3]));
    *(u16x8*)(sA + (row << 9) + (cc << 3)) = h;
  }
  __syncthreads();

  f32x4 acc[2][4];
#pragma unroll
  for (int m = 0; m < 2; ++m)
#pragma unroll
    for (int n = 0; n < 4; ++n) acc[m][n] = (f32x4){0.f, 0.f, 0.f, 0.f};

  const unsigned short* bl = Wrec + (lane << 3);
  const int nfb = (wn << 2) << 4;

  bf16x8 b0[4], b1[4];
#pragma unroll
  for (int n = 0; n < 4; ++n)
    b0[n] = *(const bf16x8*)(bl + ((nfb + (n << 4)) << 9));
  for (int kk = 0; kk < 16; kk += 2) {
#pragma unroll
    for (int n = 0; n < 4; ++n)
      b1[n] = *(const bf16x8*)(bl + ((nfb + (n << 4) + kk + 1) << 9));
    {
      const int c = (kk << 2) + lhi;
      const int slot = (c & ~7) | ((c & 7) ^ sw);
      bf16x8 af0 = *(const bf16x8*)(sA + (lrow << 9) + (slot << 3));
      bf16x8 af1 = *(const bf16x8*)(sA + ((16 + lrow) << 9) + (slot << 3));
#pragma unroll
      for (int n = 0; n < 4; ++n) {
        acc[0][n] = MFMA(af0, b0[n], acc[0][n]);
        acc[1][n] = MFMA(af1, b0[n], acc[1][n]);
      }
    }
    if (kk + 2 < 16) {
#pragma unroll
      for (int n = 0; n < 4; ++n)
        b0[n] = *(const bf16x8*)(bl + ((nfb + (n << 4) + kk + 2) << 9));
    }
    {
      const int c = ((kk + 1) << 2) + lhi;
      const int slot = (c & ~7) | ((c & 7) ^ sw);
      bf16x8 af0 = *(const bf16x8*)(sA + (lrow << 9) + (slot << 3));
      bf16x8 af1 = *(const bf16x8*)(sA + ((16 + lrow) << 9) + (slot << 3));
#pragma unroll
      for (int n = 0; n < 4; ++n) {
        acc[0][n] = MFMA(af0, b1[n], acc[0][n]);
        acc[1][n] = MFMA(af1, b1[n], acc[1][n]);
      }
    }
  }

  const int t = chain * 5 + s;
#pragma unroll
  for (int n = 0; n < 4; ++n) {
    const int col = (wn << 6) + n * 16 + lrow;
#pragma unroll
    for (int m = 0; m < 2; ++m)
#pragma unroll
      for (int q = 0; q < 4; ++q) {
        const int row = m * 16 + (lhi << 2) + q;
        const size_t gi = (rbase + row) * HID + col;
        const float x = st_in[gi];
        const float xn = x + (acc[m][n][q] - x) * INV_TAUX;
        st_out[gi] = xn;
        if (t < T_SZ)
          xsall[((size_t)row * T_SZ + t) * HID + col] = f2bf(xn);
      }
  }
}

// chain starts: st0[chain*32+b, c] = bf2f(xseq[b, 5*chain, c])
__global__ void chain_init_k(const unsigned short* __restrict__ xseq,
                             float* __restrict__ st0) {
  int idx = blockIdx.x * blockDim.x + threadIdx.x;
  if (idx >= MREC * HID) return;
  int r = idx >> 9;
  int c = idx & 511;
  int chain = r >> 5;
  int b = r & 31;
  st0[idx] = bf2f(xseq[((size_t)b * T_SZ + chain * 5) * HID + c]);
}

// weight prep into fragment-linear layout
__global__ void prep_k(const float* __restrict__ We1, const float* __restrict__ We2,
                       const float* __restrict__ We3, const float* __restrict__ Wd1,
                       const float* __restrict__ Wd2, const float* __restrict__ W,
                       unsigned short* __restrict__ wt) {
  int idx = blockIdx.x * blockDim.x + threadIdx.x;
  if (idx >= 1179648) return;
  unsigned short v;
  if (idx < 65536) {
    int i = idx, lane = (i >> 3) & 63, t2 = i >> 9;
    int kk = t2 & 3, nf = t2 >> 2;
    int n = (nf << 4) + (lane & 15), k = (kk << 5) + ((lane >> 4) << 3) + (i & 7);
    v = f2bf(We1[k * 512 + n]);
  } else if (idx < 327680) {
    int i = idx - 65536, lane = (i >> 3) & 63, t2 = i >> 9;
    int kk = t2 & 15, nf = t2 >> 4;
    int n = (nf << 4) + (lane & 15), k = (kk << 5) + ((lane >> 4) << 3) + (i & 7);
    v = f2bf(We2[k * 512 + n]);
  } else if (idx < 589824) {
    int i = idx - 327680, lane = (i >> 3) & 63, t2 = i >> 9;
    int kk = t2 & 15, nf = t2 >> 4;
    int n = (nf << 4) + (lane & 15), k = (kk << 5) + ((lane >> 4) << 3) + (i & 7);
    v = f2bf(We3[k * 512 + n]);
  } else if (idx < 851968) {
    int i = idx - 589824, lane = (i >> 3) & 63, t2 = i >> 9;
    int kk = t2 & 15, nf = t2 >> 4;
    int n = (nf << 4) + (lane & 15), k = (kk << 5) + ((lane >> 4) << 3) + (i & 7);
    v = f2bf(Wd1[k * 512 + n]);
  } else if (idx < 917504) {
    int i = idx - 851968, lane = (i >> 3) & 63, t2 = i >> 9;
    int kk = t2 & 15, nf = t2 >> 4;
    int n = (nf << 4) + (lane & 15), k = (kk << 5) + ((lane >> 4) << 3) + (i & 7);
    v = f2bf(Wd2[k * 128 + n]);
  } else {
    int i = idx - 917504, lane = (i >> 3) & 63, t2 = i >> 9;
    int kk = t2 & 15, nf = t2 >> 4;
    int n = (nf << 4) + (lane & 15), k = (kk << 5) + ((lane >> 4) << 3) + (i & 7);
    v = f2bf(W[(n << 9) + k]);
  }
  wt[idx] = v;
}

__global__ void sentinel_k(float* out, float v) { out[0] = v; }

extern "C" void kernel_launch(void* const* d_in, const int* in_sizes, int n_in,
                              void* d_out, int out_size, void* d_ws, size_t ws_size,
                              hipStream_t stream) {
  const float* in_seq = (const float*)d_in[0];
  const float* We1 = (const float*)d_in[1];
  const float* be1 = (const float*)d_in[2];
  const float* We2 = (const float*)d_in[3];
  const float* be2 = (const float*)d_in[4];
  const float* We3 = (const float*)d_in[5];
  const float* be3 = (const float*)d_in[6];
  const float* Wd1 = (const float*)d_in[7];
  const float* bd1 = (const float*)d_in[8];
  const float* Wd2 = (const float*)d_in[9];
  const float* bd2 = (const float*)d_in[10];
  const float* W   = (const float*)d_in[11];

  const int NROW = B_SZ * T_SZ;                       // 65536
  const size_t OFF_XSEQ = 0;                          // 67,108,864 B
  const size_t OFF_WT   = (size_t)NROW * HID * 2;     // 67,108,864
  const size_t OFF_ST0  = OFF_WT + 2359296;           // 69,468,160
  const size_t OFF_ST1  = OFF_ST0 + (size_t)MREC * HID * 4;  // 96,337,920
  const size_t REQUIRED = OFF_ST1 + (size_t)MREC * HID * 4;  // 123,207,680

  float* outp = (float*)d_out;
  float* outr = outp + (size_t)NROW * IN_D;

  if (ws_size < REQUIRED) {
    sentinel_k<<<1, 1, 0, stream>>>(outp, (float)(ws_size >> 20));
    return;
  }

  char* ws = (char*)d_ws;
  unsigned short* xseq = (unsigned short*)(ws + OFF_XSEQ);  // reused as xsall
  unsigned short* wt   = (unsigned short*)(ws + OFF_WT);
  unsigned short* Wd1t = wt + 589824;
  unsigned short* Wd2t = wt + 851968;
  unsigned short* Wrec = wt + 917504;
  float* st0 = (float*)(ws + OFF_ST0);
  float* st1 = (float*)(ws + OFF_ST1);

  prep_k<<<4608, 256, 0, stream>>>(We1, We2, We3, Wd1, Wd2, W, wt);
  enc_fused_k<<<1024, 512, 0, stream>>>(in_seq, wt, be1, be2, be3, xseq);
  dec_fused_k<<<1024, 512, 0, stream>>>(xseq, Wd1t, Wd2t, bd1, bd2, outr);
  chain_init_k<<<(MREC * HID + 255) / 256, 256, 0, stream>>>(xseq, st0);
  for (int s = 0; s < 5; ++s) {
    const float* sIn  = (s & 1) ? st1 : st0;
    float*       sOut = (s & 1) ? st0 : st1;
    rec2_k<<<NCHAIN, 512, 0, stream>>>(Wrec, sIn, sOut, xseq, s);
  }
  dec_fused_k<<<1024, 512, 0, stream>>>(xseq, Wd1t, Wd2t, bd1, bd2, outp);
}

// Round 10
// 437.900 us; speedup vs baseline: 2.1775x; 1.0210x over previous
//
#include <hip/hip_runtime.h>
#include <stdint.h>

#define B_SZ  32
#define T_SZ  2048
#define IN_D  128
#define HID   512
#define NCHAIN 410              // ceil(T/5)
#define MREC  (NCHAIN * B_SZ)   // 13120
#define INV_TAUX 0.005f         // 1/200

typedef __attribute__((ext_vector_type(8))) short bf16x8;
typedef __attribute__((ext_vector_type(4))) float f32x4;
typedef __attribute__((ext_vector_type(4))) float float4v;
typedef __attribute__((ext_vector_type(4))) unsigned short u16x4;
typedef __attribute__((ext_vector_type(8))) unsigned short u16x8;

// NOTE: operands SWAPPED everywhere: mfma(b, a) => D^T. Lane then holds
// row = frag_m*16 + (lane&15)  (fixed), cols = frag_n*16 + (lane>>4)*4 + q
// (4 CONSECUTIVE columns) -> all epilogues vectorize to 8B/16B stores.
#define MFMA(b, a, c) __builtin_amdgcn_mfma_f32_16x16x32_bf16((b), (a), (c), 0, 0, 0)

__device__ __forceinline__ unsigned short f2bf(float x) {
  union { float f; unsigned int u; } v; v.f = x;
  unsigned int r = v.u + 0x7FFFu + ((v.u >> 16) & 1u);  // RNE
  return (unsigned short)(r >> 16);
}
__device__ __forceinline__ float bf2f(unsigned short b) {
  union { unsigned int u; float f; } v; v.u = ((unsigned int)b) << 16;
  return v.f;
}
__device__ __forceinline__ float fast_tanh(float x) {
  float ax = fabsf(x);
  float e = __expf(-2.0f * ax);
  float r = (1.0f - e) * __builtin_amdgcn_rcpf(1.0f + e);
  return x < 0.0f ? -r : r;
}
__device__ __forceinline__ void gload_lds16(const void* g, void* l) {
  __builtin_amdgcn_global_load_lds(
      reinterpret_cast<__attribute__((address_space(1))) void*>(reinterpret_cast<uintptr_t>(g)),
      reinterpret_cast<__attribute__((address_space(3))) void*>(reinterpret_cast<uintptr_t>(l)),
      16, 0, 0);
}

// ---------------------------------------------------------------------------
// Weights FRAGMENT-LINEAR (see prep_k). 1m x 8n wave layout: wave wn owns all
// 64 rows x cols [wn*64, wn*64+64) -> zero cross-wave weight duplication.
// ---------------------------------------------------------------------------

// ---------------------------------------------------------------------------
// Fused 3-layer encoder. 512 thr = 8 waves, 64 rows/block.
// ---------------------------------------------------------------------------
__global__ __launch_bounds__(512, 2) void enc_fused_k(
    const float* __restrict__ in_seq,
    const unsigned short* __restrict__ wt,
    const float* __restrict__ be1, const float* __restrict__ be2,
    const float* __restrict__ be3,
    unsigned short* __restrict__ xseq)
{
  __shared__ __attribute__((aligned(16))) unsigned short sA[64 * 128];  // 16 KB
  __shared__ __attribute__((aligned(16))) unsigned short sH[64 * 512];  // 64 KB

  const int tid = threadIdx.x;
  const int m0 = blockIdx.x * 64;
  const int wave = tid >> 6, lane = tid & 63;
  const int wn = wave;
  const int lrow = lane & 15, lhi = lane >> 4, sw = lrow & 7;

  // stage input tile f32 -> bf16, chunk-swizzled
#pragma unroll
  for (int p = 0; p < 2; ++p) {
    int id = (p << 9) + tid;
    int row = id >> 4, cc = id & 15;
    const float* src = in_seq + (size_t)(m0 + row) * IN_D + (cc << 3);
    float4v u0 = *(const float4v*)src;
    float4v u1 = *(const float4v*)(src + 4);
    u16x8 h;
    h[0] = f2bf(u0[0]); h[1] = f2bf(u0[1]); h[2] = f2bf(u0[2]); h[3] = f2bf(u0[3]);
    h[4] = f2bf(u1[0]); h[5] = f2bf(u1[1]); h[6] = f2bf(u1[2]); h[7] = f2bf(u1[3]);
    int slot = (cc & 8) | ((cc & 7) ^ (row & 7));
    *(u16x8*)(sA + (row << 7) + (slot << 3)) = h;
  }
  __syncthreads();

  f32x4 acc[4][4];
  const unsigned short* Bts[3] = {wt, wt + 65536, wt + 327680};
  const float* bss[3] = {be1, be2, be3};

  for (int l = 0; l < 3; ++l) {
    const unsigned short* lsrc = (l == 0) ? sA : sH;
    const int lstr = (l == 0) ? 128 : 512;
    const int nk = (l == 0) ? 4 : 16;
    const unsigned short* bl = Bts[l] + (lane << 3);
    const int nfb = (wn << 2) * nk;
    const float* bias = bss[l];

#pragma unroll
    for (int m = 0; m < 4; ++m)
#pragma unroll
      for (int n = 0; n < 4; ++n) acc[m][n] = (f32x4){0.f, 0.f, 0.f, 0.f};

    bf16x8 b0[4], b1[4];
#pragma unroll
    for (int n = 0; n < 4; ++n)
      b0[n] = *(const bf16x8*)(bl + ((nfb + n * nk) << 9));

    for (int kk = 0; kk < nk; kk += 2) {
#pragma unroll
      for (int n = 0; n < 4; ++n)
        b1[n] = *(const bf16x8*)(bl + ((nfb + n * nk + kk + 1) << 9));
      {
        const int c = (kk << 2) + lhi;
        const int slot = (c & ~7) | ((c & 7) ^ sw);
        bf16x8 af[4];
#pragma unroll
        for (int m = 0; m < 4; ++m)
          af[m] = *(const bf16x8*)(lsrc + (m * 16 + lrow) * lstr + (slot << 3));
#pragma unroll
        for (int n = 0; n < 4; ++n)
#pragma unroll
          for (int m = 0; m < 4; ++m)
            acc[m][n] = MFMA(b0[n], af[m], acc[m][n]);
      }
      if (kk + 2 < nk) {
#pragma unroll
        for (int n = 0; n < 4; ++n)
          b0[n] = *(const bf16x8*)(bl + ((nfb + n * nk + kk + 2) << 9));
      }
      {
        const int c = ((kk + 1) << 2) + lhi;
        const int slot = (c & ~7) | ((c & 7) ^ sw);
        bf16x8 af[4];
#pragma unroll
        for (int m = 0; m < 4; ++m)
          af[m] = *(const bf16x8*)(lsrc + (m * 16 + lrow) * lstr + (slot << 3));
#pragma unroll
        for (int n = 0; n < 4; ++n)
#pragma unroll
          for (int m = 0; m < 4; ++m)
            acc[m][n] = MFMA(b1[n], af[m], acc[m][n]);
      }
    }
    __syncthreads();
    // epilogue: acc[m][n][q] = D[row=m*16+lrow][col=wn*64+n*16+lhi*4+q]
#pragma unroll
    for (int n = 0; n < 4; ++n) {
      const int col0 = (wn << 6) + n * 16 + (lhi << 2);
      const float4v bv = *(const float4v*)(bias + col0);
      const int c2 = col0 >> 3;
#pragma unroll
      for (int m = 0; m < 4; ++m) {
        const int row = m * 16 + lrow;
        const int slot2 = (c2 & ~7) | ((c2 & 7) ^ (row & 7));
        u16x4 h;
#pragma unroll
        for (int q = 0; q < 4; ++q) h[q] = f2bf(fast_tanh(acc[m][n][q] + bv[q]));
        *(u16x4*)(sH + (row << 9) + (slot2 << 3) + (col0 & 7)) = h;
      }
    }
    __syncthreads();
  }

  // coalesced un-swizzling copy sH -> xseq
#pragma unroll
  for (int p = 0; p < 8; ++p) {
    int id = (p << 9) + tid;
    int row = id >> 6, cc = id & 63;
    int slot = (cc & ~7) | ((cc & 7) ^ (row & 7));
    u16x8 v = *(const u16x8*)(sH + (row << 9) + (slot << 3));
    *(u16x8*)(xseq + ((size_t)(m0 + row) << 9) + (cc << 3)) = v;
  }
}

// ---------------------------------------------------------------------------
// Fused 2-layer decoder. 512 thr = 8 waves, 64 rows/block, 1m x 8n.
// ---------------------------------------------------------------------------
__global__ __launch_bounds__(512, 2) void dec_fused_k(
    const unsigned short* __restrict__ X,
    const unsigned short* __restrict__ Wd1t,
    const unsigned short* __restrict__ Wd2t,
    const float* __restrict__ bd1, const float* __restrict__ bd2,
    float* __restrict__ out)
{
  __shared__ __attribute__((aligned(16))) unsigned short sX[64 * 512];  // 64 KB
  __shared__ __attribute__((aligned(16))) unsigned short sH[64 * 512];  // 64 KB

  const int tid = threadIdx.x;
  const int m0 = blockIdx.x * 64;
  const int wave = tid >> 6, lane = tid & 63;
  const int wn = wave;
  const int lrow = lane & 15, lhi = lane >> 4, sw = lrow & 7;

  char* lX = (char*)sX + tid * 16;
#pragma unroll
  for (int p = 0; p < 8; ++p) {
    int id = (p << 9) + tid;
    int row = id >> 6, cc = id & 63;
    int gcc = (cc & ~7) | ((cc & 7) ^ (row & 7));
    gload_lds16(X + ((size_t)(m0 + row) << 9) + (gcc << 3), lX + (p << 13));
  }
  __syncthreads();

  // ---- layer 1: K=512, N=512 ----
  f32x4 acc[4][4];
#pragma unroll
  for (int m = 0; m < 4; ++m)
#pragma unroll
    for (int n = 0; n < 4; ++n) acc[m][n] = (f32x4){0.f, 0.f, 0.f, 0.f};

  {
    const unsigned short* bl = Wd1t + (lane << 3);
    const int nfb = (wn << 2) << 4;
    bf16x8 b0[4], b1[4];
#pragma unroll
    for (int n = 0; n < 4; ++n)
      b0[n] = *(const bf16x8*)(bl + ((nfb + (n << 4)) << 9));
    for (int kk = 0; kk < 16; kk += 2) {
#pragma unroll
      for (int n = 0; n < 4; ++n)
        b1[n] = *(const bf16x8*)(bl + ((nfb + (n << 4) + kk + 1) << 9));
      {
        const int c = (kk << 2) + lhi;
        const int slot = (c & ~7) | ((c & 7) ^ sw);
        bf16x8 af[4];
#pragma unroll
        for (int m = 0; m < 4; ++m)
          af[m] = *(const bf16x8*)(sX + ((m * 16 + lrow) << 9) + (slot << 3));
#pragma unroll
        for (int n = 0; n < 4; ++n)
#pragma unroll
          for (int m = 0; m < 4; ++m)
            acc[m][n] = MFMA(b0[n], af[m], acc[m][n]);
      }
      if (kk + 2 < 16) {
#pragma unroll
        for (int n = 0; n < 4; ++n)
          b0[n] = *(const bf16x8*)(bl + ((nfb + (n << 4) + kk + 2) << 9));
      }
      {
        const int c = ((kk + 1) << 2) + lhi;
        const int slot = (c & ~7) | ((c & 7) ^ sw);
        bf16x8 af[4];
#pragma unroll
        for (int m = 0; m < 4; ++m)
          af[m] = *(const bf16x8*)(sX + ((m * 16 + lrow) << 9) + (slot << 3));
#pragma unroll
        for (int n = 0; n < 4; ++n)
#pragma unroll
          for (int m = 0; m < 4; ++m)
            acc[m][n] = MFMA(b1[n], af[m], acc[m][n]);
      }
    }
  }
  __syncthreads();
#pragma unroll
  for (int n = 0; n < 4; ++n) {
    const int col0 = (wn << 6) + n * 16 + (lhi << 2);
    const float4v bv = *(const float4v*)(bd1 + col0);
    const int c2 = col0 >> 3;
#pragma unroll
    for (int m = 0; m < 4; ++m) {
      const int row = m * 16 + lrow;
      const int slot2 = (c2 & ~7) | ((c2 & 7) ^ (row & 7));
      u16x4 h;
#pragma unroll
      for (int q = 0; q < 4; ++q) h[q] = f2bf(fast_tanh(acc[m][n][q] + bv[q]));
      *(u16x4*)(sH + (row << 9) + (slot2 << 3) + (col0 & 7)) = h;
    }
  }
  __syncthreads();

  // ---- layer 2: K=512, N=128; wave owns one 16-col frag (nf = wn) ----
  f32x4 acc2[4];
#pragma unroll
  for (int m = 0; m < 4; ++m) acc2[m] = (f32x4){0.f, 0.f, 0.f, 0.f};

  {
    const unsigned short* bl = Wd2t + (lane << 3);
    const int nfb = wn << 4;
    bf16x8 c0, c1;
    c0 = *(const bf16x8*)(bl + ((nfb + 0) << 9));
    for (int kk = 0; kk < 16; kk += 2) {
      c1 = *(const bf16x8*)(bl + ((nfb + kk + 1) << 9));
      {
        const int c = (kk << 2) + lhi;
        const int slot = (c & ~7) | ((c & 7) ^ sw);
#pragma unroll
        for (int m = 0; m < 4; ++m) {
          bf16x8 af = *(const bf16x8*)(sH + ((m * 16 + lrow) << 9) + (slot << 3));
          acc2[m] = MFMA(c0, af, acc2[m]);
        }
      }
      if (kk + 2 < 16)
        c0 = *(const bf16x8*)(bl + ((nfb + kk + 2) << 9));
      {
        const int c = ((kk + 1) << 2) + lhi;
        const int slot = (c & ~7) | ((c & 7) ^ sw);
#pragma unroll
        for (int m = 0; m < 4; ++m) {
          bf16x8 af = *(const bf16x8*)(sH + ((m * 16 + lrow) << 9) + (slot << 3));
          acc2[m] = MFMA(c1, af, acc2[m]);
        }
      }
    }
  }
  // epilogue 2: lane holds row=m*16+lrow, cols = wn*16+lhi*4+q -> float4 store
  {
    const int col0 = (wn << 4) + (lhi << 2);
    const float4v bv = *(const float4v*)(bd2 + col0);
#pragma unroll
    for (int m = 0; m < 4; ++m) {
      const int row = m * 16 + lrow;
      float4v o;
#pragma unroll
      for (int q = 0; q < 4; ++q) o[q] = fast_tanh(acc2[m][q] + bv[q]);
      *(float4v*)(out + (size_t)(m0 + row) * IN_D + col0) = o;
    }
  }
}

// ---------------------------------------------------------------------------
// Recurrence step: block = one chain (32 rows x 512), 8 waves over N=512.
// ---------------------------------------------------------------------------
__global__ __launch_bounds__(512, 2) void rec2_k(
    const unsigned short* __restrict__ Wrec,
    const float* __restrict__ st_in,
    float* __restrict__ st_out,
    unsigned short* __restrict__ xsall,
    int s)
{
  __shared__ __attribute__((aligned(16))) unsigned short sA[32 * 512];  // 32 KB

  const int tid = threadIdx.x;
  const int chain = blockIdx.x;
  const int wave = tid >> 6, lane = tid & 63;
  const int wn = wave;
  const int lrow = lane & 15, lhi = lane >> 4, sw = lrow & 7;
  const size_t rbase = (size_t)chain * 32;

#pragma unroll
  for (int p = 0; p < 4; ++p) {
    int id = (p << 9) + tid;
    int row = id >> 6, cc = id & 63;
    int gc = (cc & ~7) | ((cc & 7) ^ (row & 7));
    const float* src = st_in + (rbase + row) * HID + (gc << 3);
    float4v u0 = *(const float4v*)src;
    float4v u1 = *(const float4v*)(src + 4);
    u16x8 h;
    h[0] = f2bf(fast_tanh(u0[0])); h[1] = f2bf(fast_tanh(u0[1]));
    h[2] = f2bf(fast_tanh(u0[2])); h[3] = f2bf(fast_tanh(u0[3]));
    h[4] = f2bf(fast_tanh(u1[0])); h[5] = f2bf(fast_tanh(u1[1]));
    h[6] = f2bf(fast_tanh(u1[2])); h[7] = f2bf(fast_tanh(u1[3]));
    *(u16x8*)(sA + (row << 9) + (cc << 3)) = h;
  }
  __syncthreads();

  f32x4 acc[2][4];
#pragma unroll
  for (int m = 0; m < 2; ++m)
#pragma unroll
    for (int n = 0; n < 4; ++n) acc[m][n] = (f32x4){0.f, 0.f, 0.f, 0.f};

  const unsigned short* bl = Wrec + (lane << 3);
  const int nfb = (wn << 2) << 4;

  bf16x8 b0[4], b1[4];
#pragma unroll
  for (int n = 0; n < 4; ++n)
    b0[n] = *(const bf16x8*)(bl + ((nfb + (n << 4)) << 9));
  for (int kk = 0; kk < 16; kk += 2) {
#pragma unroll
    for (int n = 0; n < 4; ++n)
      b1[n] = *(const bf16x8*)(bl + ((nfb + (n << 4) + kk + 1) << 9));
    {
      const int c = (kk << 2) + lhi;
      const int slot = (c & ~7) | ((c & 7) ^ sw);
      bf16x8 af0 = *(const bf16x8*)(sA + (lrow << 9) + (slot << 3));
      bf16x8 af1 = *(const bf16x8*)(sA + ((16 + lrow) << 9) + (slot << 3));
#pragma unroll
      for (int n = 0; n < 4; ++n) {
        acc[0][n] = MFMA(b0[n], af0, acc[0][n]);
        acc[1][n] = MFMA(b0[n], af1, acc[1][n]);
      }
    }
    if (kk + 2 < 16) {
#pragma unroll
      for (int n = 0; n < 4; ++n)
        b0[n] = *(const bf16x8*)(bl + ((nfb + (n << 4) + kk + 2) << 9));
    }
    {
      const int c = ((kk + 1) << 2) + lhi;
      const int slot = (c & ~7) | ((c & 7) ^ sw);
      bf16x8 af0 = *(const bf16x8*)(sA + (lrow << 9) + (slot << 3));
      bf16x8 af1 = *(const bf16x8*)(sA + ((16 + lrow) << 9) + (slot << 3));
#pragma unroll
      for (int n = 0; n < 4; ++n) {
        acc[0][n] = MFMA(b1[n], af0, acc[0][n]);
        acc[1][n] = MFMA(b1[n], af1, acc[1][n]);
      }
    }
  }

  // epilogue: lane holds row=m*16+lrow, cols=wn*64+n*16+lhi*4+q (vectorized)
  const int t = chain * 5 + s;
#pragma unroll
  for (int n = 0; n < 4; ++n) {
    const int col0 = (wn << 6) + n * 16 + (lhi << 2);
#pragma unroll
    for (int m = 0; m < 2; ++m) {
      const int row = m * 16 + lrow;
      const size_t gi = (rbase + row) * HID + col0;
      float4v x = *(const float4v*)(st_in + gi);
      float4v xn;
#pragma unroll
      for (int q = 0; q < 4; ++q) xn[q] = x[q] + (acc[m][n][q] - x[q]) * INV_TAUX;
      *(float4v*)(st_out + gi) = xn;
      if (t < T_SZ) {
        u16x4 h;
#pragma unroll
        for (int q = 0; q < 4; ++q) h[q] = f2bf(xn[q]);
        *(u16x4*)(xsall + ((size_t)row * T_SZ + t) * HID + col0) = h;
      }
    }
  }
}

// chain starts: st0[chain*32+b, c] = bf2f(xseq[b, 5*chain, c])
__global__ void chain_init_k(const unsigned short* __restrict__ xseq,
                             float* __restrict__ st0) {
  int idx = blockIdx.x * blockDim.x + threadIdx.x;
  if (idx >= MREC * HID) return;
  int r = idx >> 9;
  int c = idx & 511;
  int chain = r >> 5;
  int b = r & 31;
  st0[idx] = bf2f(xseq[((size_t)b * T_SZ + chain * 5) * HID + c]);
}

// weight prep into fragment-linear layout:
// flat[((nf*nk+kk)*64+lane)*8+e] = B[nf*16+(lane&15)][kk*32+(lane>>4)*8+e]
__global__ void prep_k(const float* __restrict__ We1, const float* __restrict__ We2,
                       const float* __restrict__ We3, const float* __restrict__ Wd1,
                       const float* __restrict__ Wd2, const float* __restrict__ W,
                       unsigned short* __restrict__ wt) {
  int idx = blockIdx.x * blockDim.x + threadIdx.x;
  if (idx >= 1179648) return;
  unsigned short v;
  if (idx < 65536) {
    int i = idx, lane = (i >> 3) & 63, t2 = i >> 9;
    int kk = t2 & 3, nf = t2 >> 2;
    int n = (nf << 4) + (lane & 15), k = (kk << 5) + ((lane >> 4) << 3) + (i & 7);
    v = f2bf(We1[k * 512 + n]);
  } else if (idx < 327680) {
    int i = idx - 65536, lane = (i >> 3) & 63, t2 = i >> 9;
    int kk = t2 & 15, nf = t2 >> 4;
    int n = (nf << 4) + (lane & 15), k = (kk << 5) + ((lane >> 4) << 3) + (i & 7);
    v = f2bf(We2[k * 512 + n]);
  } else if (idx < 589824) {
    int i = idx - 327680, lane = (i >> 3) & 63, t2 = i >> 9;
    int kk = t2 & 15, nf = t2 >> 4;
    int n = (nf << 4) + (lane & 15), k = (kk << 5) + ((lane >> 4) << 3) + (i & 7);
    v = f2bf(We3[k * 512 + n]);
  } else if (idx < 851968) {
    int i = idx - 589824, lane = (i >> 3) & 63, t2 = i >> 9;
    int kk = t2 & 15, nf = t2 >> 4;
    int n = (nf << 4) + (lane & 15), k = (kk << 5) + ((lane >> 4) << 3) + (i & 7);
    v = f2bf(Wd1[k * 512 + n]);
  } else if (idx < 917504) {
    int i = idx - 851968, lane = (i >> 3) & 63, t2 = i >> 9;
    int kk = t2 & 15, nf = t2 >> 4;
    int n = (nf << 4) + (lane & 15), k = (kk << 5) + ((lane >> 4) << 3) + (i & 7);
    v = f2bf(Wd2[k * 128 + n]);
  } else {
    int i = idx - 917504, lane = (i >> 3) & 63, t2 = i >> 9;
    int kk = t2 & 15, nf = t2 >> 4;
    int n = (nf << 4) + (lane & 15), k = (kk << 5) + ((lane >> 4) << 3) + (i & 7);
    v = f2bf(W[(n << 9) + k]);
  }
  wt[idx] = v;
}

__global__ void sentinel_k(float* out, float v) { out[0] = v; }

extern "C" void kernel_launch(void* const* d_in, const int* in_sizes, int n_in,
                              void* d_out, int out_size, void* d_ws, size_t ws_size,
                              hipStream_t stream) {
  const float* in_seq = (const float*)d_in[0];
  const float* We1 = (const float*)d_in[1];
  const float* be1 = (const float*)d_in[2];
  const float* We2 = (const float*)d_in[3];
  const float* be2 = (const float*)d_in[4];
  const float* We3 = (const float*)d_in[5];
  const float* be3 = (const float*)d_in[6];
  const float* Wd1 = (const float*)d_in[7];
  const float* bd1 = (const float*)d_in[8];
  const float* Wd2 = (const float*)d_in[9];
  const float* bd2 = (const float*)d_in[10];
  const float* W   = (const float*)d_in[11];

  const int NROW = B_SZ * T_SZ;                       // 65536
  const size_t OFF_XSEQ = 0;                          // 67,108,864 B
  const size_t OFF_WT   = (size_t)NROW * HID * 2;     // 67,108,864
  const size_t OFF_ST0  = OFF_WT + 2359296;           // 69,468,160
  const size_t OFF_ST1  = OFF_ST0 + (size_t)MREC * HID * 4;  // 96,337,920
  const size_t REQUIRED = OFF_ST1 + (size_t)MREC * HID * 4;  // 123,207,680

  float* outp = (float*)d_out;
  float* outr = outp + (size_t)NROW * IN_D;

  if (ws_size < REQUIRED) {
    sentinel_k<<<1, 1, 0, stream>>>(outp, (float)(ws_size >> 20));
    return;
  }

  char* ws = (char*)d_ws;
  unsigned short* xseq = (unsigned short*)(ws + OFF_XSEQ);  // reused as xsall
  unsigned short* wt   = (unsigned short*)(ws + OFF_WT);
  unsigned short* Wd1t = wt + 589824;
  unsigned short* Wd2t = wt + 851968;
  unsigned short* Wrec = wt + 917504;
  float* st0 = (float*)(ws + OFF_ST0);
  float* st1 = (float*)(ws + OFF_ST1);

  prep_k<<<4608, 256, 0, stream>>>(We1, We2, We3, Wd1, Wd2, W, wt);
  enc_fused_k<<<1024, 512, 0, stream>>>(in_seq, wt, be1, be2, be3, xseq);
  dec_fused_k<<<1024, 512, 0, stream>>>(xseq, Wd1t, Wd2t, bd1, bd2, outr);
  chain_init_k<<<(MREC * HID + 255) / 256, 256, 0, stream>>>(xseq, st0);
  for (int s = 0; s < 5; ++s) {
    const float* sIn  = (s & 1) ? st1 : st0;
    float*       sOut = (s & 1) ? st0 : st1;
    rec2_k<<<NCHAIN, 512, 0, stream>>>(Wrec, sIn, sOut, xseq, s);
  }
  dec_fused_k<<<1024, 512, 0, stream>>>(xseq, Wd1t, Wd2t, bd1, bd2, outp);
}